// Round 6
// baseline (2009.086 us; speedup 1.0000x reference)
//
#include <hip/hip_runtime.h>
#include <cstdint>
#include <cstddef>

// ---------------- problem constants ----------------
#define TSTEPS 192
#define BATCH  4096
#define FRAW   20
#define FCONV  22
#define FCNN   11
#define HID    40
#define NOUT   21
#define ROWSPB 16
#define NTH    64               // ONE wave per block: barrier-free recurrence
#define NBLK   (BATCH/ROWSPB)   // 256 blocks -> 1 wave per CU

#define FEAT_OFF 4096           // ws: [0,1536) stats ; feat at byte offset 4096

typedef _Float16 half8 __attribute__((ext_vector_type(8)));
typedef float    f32x4 __attribute__((ext_vector_type(4)));
#define MFMA16(a,b,c) __builtin_amdgcn_mfma_f32_16x16x32_f16(a,b,c,0,0,0)
// compiler-only fence: LDS ops are per-wave in-order in HW; this stops the
// compiler from reordering thread-locally-"independent" ds ops across the
// cross-lane exchange points. Zero runtime cost.
#define LDSFENCE() do{ asm volatile("" ::: "memory"); __builtin_amdgcn_sched_barrier(0); }while(0)

__device__ __forceinline__ float sigm_(float x){ return 1.f/(1.f+__expf(-x)); }
__device__ __forceinline__ float tanh_(float x){ float e=__expf(2.f*x); return 1.f-2.f/(e+1.f); }
__device__ __forceinline__ float softplus_(float x){ return fmaxf(x,0.f)+log1pf(__expf(-fabsf(x))); }

// fragment-layout offset (halves) of logical k, row mr:
// [chunk=k>>5][q=(k>>3)&3][mr][i=k&7]; chunk stride 512, q stride 128
__device__ __forceinline__ int offk(int k, int mr){
    return ((k>>5)*4 + ((k>>3)&3))*128 + mr*8 + (k&7);
}

// -------- kernel 1: per-t BN affine params (unchanged) ----------------------
__global__ __launch_bounds__(256)
void stats_kernel(const float* __restrict__ x_enc, const float* __restrict__ y_enc,
                  const float* __restrict__ conv_w, const float* __restrict__ conv_b,
                  const float* __restrict__ bn_w, const float* __restrict__ bn_b,
                  float* __restrict__ stats)
{
    const int t = blockIdx.x;
    const float w0=conv_w[0], w1=conv_w[1], w2=conv_w[2], cb=conv_b[0];
    const float* src = (t < 96) ? (x_enc + (size_t)t*21) : (y_enc + (size_t)(t-96)*21);
    float s=0.f, ss=0.f;
    for (int b = threadIdx.x; b < BATCH; b += 256) {
        const float* xr = src + (size_t)b*2016;
        float xv[FRAW];
        #pragma unroll
        for (int f=0; f<FRAW; ++f) xv[f] = xr[f];
        #pragma unroll
        for (int i=0; i<FCONV; ++i) {
            float y = fmaf(w0, xv[(i+18)%20], fmaf(w1, xv[(i+19)%20], fmaf(w2, xv[i%20], cb)));
            s += y; ss = fmaf(y, y, ss);
        }
    }
    __shared__ float rs[256], rq[256];
    rs[threadIdx.x]=s; rq[threadIdx.x]=ss;
    __syncthreads();
    for (int o=128; o>0; o>>=1){
        if (threadIdx.x < o){ rs[threadIdx.x]+=rs[threadIdx.x+o]; rq[threadIdx.x]+=rq[threadIdx.x+o]; }
        __syncthreads();
    }
    if (threadIdx.x == 0){
        const float N = (float)(BATCH*FCONV);
        float mu  = rs[0]/N;
        float var = rq[0]/N - mu*mu;
        float A   = rsqrtf(var + 1e-5f) * bn_w[0];
        stats[2*t]   = A;
        stats[2*t+1] = bn_b[0] - mu*A;
    }
}

// -------- kernel 2: conv + BN + ELU + maxpool (unchanged) -------------------
__global__ __launch_bounds__(256)
void feat_kernel(const float* __restrict__ x_enc, const float* __restrict__ y_enc,
                 const float* __restrict__ conv_w, const float* __restrict__ conv_b,
                 const float* __restrict__ stats, float* __restrict__ feat)
{
    const int t = blockIdx.x;
    const int b = blockIdx.y*256 + threadIdx.x;
    const float w0=conv_w[0], w1=conv_w[1], w2=conv_w[2], cb=conv_b[0];
    const float A = stats[2*t], Bc = stats[2*t+1];
    const float* xr = ((t<96) ? (x_enc + (size_t)t*21) : (y_enc + (size_t)(t-96)*21)) + (size_t)b*2016;
    float xv[FRAW];
    #pragma unroll
    for (int f=0; f<FRAW; ++f) xv[f] = xr[f];
    float yv[FCONV];
    #pragma unroll
    for (int i=0; i<FCONV; ++i) {
        float y = fmaf(w0, xv[(i+18)%20], fmaf(w1, xv[(i+19)%20], fmaf(w2, xv[i%20], cb)));
        y = fmaf(y, A, Bc);
        yv[i] = (y > 0.f) ? y : expm1f(y);
    }
    float* fo = feat + ((size_t)t*BATCH + b)*FCNN;
    #pragma unroll
    for (int i=0; i<FCNN; ++i) {
        float m = (i==0) ? fmaxf(yv[0], yv[1])
                         : fmaxf(yv[2*i-1], fmaxf(yv[2*i], yv[2*i+1]));
        fo[i] = m;
    }
}

// -------- kernel 3: barrier-free single-wave MFMA LSTM ----------------------
// 256 blocks x 64 threads (1 wave), 1 wave/CU, 16 rows/wave, all 160 gates
// per wave (10 tiles in registers). One x-buffer K=96 in fragment layout:
//   k 0..10 feat(t) | 11..50 h0 | 51..90 h1 | 91..95 pad
// L0 reads chunks 0-1 (A zeros k>=51). L1/heads use A-frags k-shifted by 11
// (free: A lives in VGPRs). Intra-wave LDS is in-order -> no s_barrier.
__global__ __launch_bounds__(NTH, 1)
void lstm_kernel(const float* __restrict__ feat,
                 const float* __restrict__ w_ih0, const float* __restrict__ w_hh0, const float* __restrict__ b0,
                 const float* __restrict__ w_ih1, const float* __restrict__ w_hh1, const float* __restrict__ b1,
                 const float* __restrict__ w_gamma, const float* __restrict__ b_gamma,
                 const float* __restrict__ w_eta,   const float* __restrict__ b_eta,
                 float* __restrict__ out)
{
    __shared__ __align__(16) _Float16 Xh[3*512];   // hi plane, 3 chunks
    __shared__ __align__(16) _Float16 Xl[3*512];   // lo plane

    const int tid  = threadIdx.x;
    const int l    = tid & 63;
    const int q    = l >> 4;
    const int mr   = l & 15;
    const int row0 = blockIdx.x * ROWSPB;

    // ---- zero LDS (single wave: instruction order = full order) ----
    { uint32_t* z=(uint32_t*)Xh; for(int i=tid;i<768;i+=NTH) z[i]=0u;
      z=(uint32_t*)Xl;           for(int i=tid;i<768;i+=NTH) z[i]=0u; }

    // ---- A fragments in registers (hi/lo split), 10 tiles ----
    // tile g = units 4g..4g+3; A row mr -> unit 4g+(mr>>2), gate mr&3;
    // torch row RA = gate*40 + unit. D layout: lane(q,mr) gets unit 4g+q,
    // gates i,f,g,o in acc[0..3] (proven R4/R5).
    half8 aL0h[10][2], aL0l[10][2], aL1h[10][3], aL1l[10][3], aHd[2][3];
    #pragma unroll
    for (int g=0; g<10; ++g){
        const int uAg = 4*g + (mr >> 2);
        const int RA  = (mr & 3)*40 + uAg;
        #pragma unroll
        for (int c=0; c<2; ++c){
            #pragma unroll
            for (int i=0; i<8; ++i){
                int k = 32*c + 8*q + i;
                float v = (k<11) ? w_ih0[RA*11+k] : ((k<51) ? w_hh0[RA*40+k-11] : 0.f);
                _Float16 h = (_Float16)v;
                aL0h[g][c][i]=h; aL0l[g][c][i]=(_Float16)(v-(float)h);
            }
        }
        #pragma unroll
        for (int c=0; c<3; ++c){
            #pragma unroll
            for (int i=0; i<8; ++i){
                int k1 = 32*c + 8*q + i - 11;           // shift by 11 into [h0|h1]
                float v = (k1>=0 && k1<40) ? w_ih1[RA*40+k1]
                        : ((k1>=40 && k1<80) ? w_hh1[RA*40+k1-40] : 0.f);
                _Float16 h = (_Float16)v;
                aL1h[g][c][i]=h; aL1l[g][c][i]=(_Float16)(v-(float)h);
            }
        }
    }
    #pragma unroll
    for (int g2=0; g2<2; ++g2){
        int jo = 16*g2 + mr;
        #pragma unroll
        for (int c=0; c<3; ++c){
            #pragma unroll
            for (int i=0; i<8; ++i){
                int k1 = 32*c + 8*q + i - 11;
                float v = 0.f;
                if (jo < NOUT && k1 >= 0 && k1 < 80){
                    int col = (k1<40) ? 2*k1 : 2*(k1-40)+1;   // hp interleave folded
                    v = (jo==0) ? w_gamma[col] : w_eta[(jo-1)*80 + col];
                }
                aHd[g2][c][i] = (_Float16)v;
            }
        }
    }

    // ---- biases ----
    f32x4 bias0[10], bias1[10], biash[2];
    #pragma unroll
    for (int g=0; g<10; ++g){
        int u = 4*g + q;
        bias0[g][0]=b0[u]; bias0[g][1]=b0[40+u]; bias0[g][2]=b0[80+u]; bias0[g][3]=b0[120+u];
        bias1[g][0]=b1[u]; bias1[g][1]=b1[40+u]; bias1[g][2]=b1[80+u]; bias1[g][3]=b1[120+u];
    }
    #pragma unroll
    for (int g2=0; g2<2; ++g2){
        #pragma unroll
        for (int e=0; e<4; ++e){
            int jo = 16*g2 + 4*q + e;
            biash[g2][e] = (jo < NOUT) ? ((jo==0) ? b_gamma[0] : b_eta[jo-1]) : 0.f;
        }
    }

    // ---- per-thread h write offsets ----
    int woH0[10], woH1[10];
    #pragma unroll
    for (int g=0; g<10; ++g){
        woH0[g] = offk(11 + 4*g + q, mr);   // h0 region
        woH1[g] = offk(51 + 4*g + q, mr);   // h1 region
    }

    // ---- feat staging map: 176 elems, lane handles idx = l, l+64, l+128 ----
    int fW[3]; bool fV[3]; const float* fG[3];
    #pragma unroll
    for (int s=0; s<3; ++s){
        int idx = l + 64*s;
        fV[s] = (idx < ROWSPB*FCNN);
        int r = idx/11, f = idx - 11*r;
        r &= 15;
        fW[s] = offk(f, r);
        fG[s] = feat + (size_t)(row0 + r)*FCNN + f;
    }

    LDSFENCE();
    // stage feat(0)
    #pragma unroll
    for (int s=0; s<3; ++s) if (fV[s]){
        float v = fG[s][0];
        _Float16 h = (_Float16)v;
        Xh[fW[s]] = h; Xl[fW[s]] = (_Float16)(v - (float)h);
    }
    LDSFENCE();

    float c0[10], c1[10];
    #pragma unroll
    for (int g=0; g<10; ++g){ c0[g]=0.f; c1[g]=0.f; }

    for (int t=0; t<TSTEPS; ++t){
        // global prefetch feat(t+1) (consumed end of step)
        float fpre[3];
        #pragma unroll
        for (int s=0; s<3; ++s)
            fpre[s] = (fV[s] && t+1 < TSTEPS) ? fG[s][(size_t)(t+1)*BATCH*FCNN] : 0.f;

        // ---- read pre-update frags: feat(t) | h0(t-1) | h1(t-1) ----
        half8 xh0 = *(const half8*)(Xh + l*8);
        half8 xh1 = *(const half8*)(Xh + 512 + l*8);
        half8 xh2 = *(const half8*)(Xh + 1024 + l*8);
        half8 xl0 = *(const half8*)(Xl + l*8);
        half8 xl1 = *(const half8*)(Xl + 512 + l*8);

        // ---- heads on h(t-1) (A zeros feat region; hi-only, proven R5) ----
        f32x4 H0 = biash[0], H1 = biash[1];
        H0 = MFMA16(aHd[0][0], xh0, H0);  H1 = MFMA16(aHd[1][0], xh0, H1);
        H0 = MFMA16(aHd[0][1], xh1, H0);  H1 = MFMA16(aHd[1][1], xh1, H1);
        H0 = MFMA16(aHd[0][2], xh2, H0);  H1 = MFMA16(aHd[1][2], xh2, H1);

        // ---- layer0: chunks 0-1, triple hi/lo product, 10 tiles ----
        #pragma unroll
        for (int g=0; g<10; ++g){
            f32x4 acc = bias0[g];
            acc = MFMA16(aL0h[g][0], xh0, acc);
            acc = MFMA16(aL0l[g][0], xh0, acc);
            acc = MFMA16(aL0h[g][0], xl0, acc);
            acc = MFMA16(aL0h[g][1], xh1, acc);
            acc = MFMA16(aL0l[g][1], xh1, acc);
            acc = MFMA16(aL0h[g][1], xl1, acc);
            float ig=sigm_(acc[0]), fg=sigm_(acc[1]), gv=tanh_(acc[2]), og=sigm_(acc[3]);
            c0[g] = fmaf(fg, c0[g], ig*gv);
            float h0v = og * tanh_(c0[g]);
            _Float16 hh=(_Float16)h0v, hl=(_Float16)(h0v-(float)hh);
            Xh[woH0[g]] = hh; Xl[woH0[g]] = hl;
        }
        LDSFENCE();   // cross-lane exchange point (HW DS pipe is in-order)

        // ---- re-read: feat(t) | h0(t) | h1(t-1) ----
        half8 yh0 = *(const half8*)(Xh + l*8);
        half8 yh1 = *(const half8*)(Xh + 512 + l*8);
        half8 yh2 = *(const half8*)(Xh + 1024 + l*8);
        half8 yl0 = *(const half8*)(Xl + l*8);
        half8 yl1 = *(const half8*)(Xl + 512 + l*8);
        half8 yl2 = *(const half8*)(Xl + 1024 + l*8);

        // ---- layer1: 3 chunks, A shifted by 11 (zeros feat region) ----
        #pragma unroll
        for (int g=0; g<10; ++g){
            f32x4 acc = bias1[g];
            acc = MFMA16(aL1h[g][0], yh0, acc);
            acc = MFMA16(aL1l[g][0], yh0, acc);
            acc = MFMA16(aL1h[g][0], yl0, acc);
            acc = MFMA16(aL1h[g][1], yh1, acc);
            acc = MFMA16(aL1l[g][1], yh1, acc);
            acc = MFMA16(aL1h[g][1], yl1, acc);
            acc = MFMA16(aL1h[g][2], yh2, acc);
            acc = MFMA16(aL1l[g][2], yh2, acc);
            acc = MFMA16(aL1h[g][2], yl2, acc);
            float ig=sigm_(acc[0]), fg=sigm_(acc[1]), gv=tanh_(acc[2]), og=sigm_(acc[3]);
            c1[g] = fmaf(fg, c1[g], ig*gv);
            float h1v = og * tanh_(c1[g]);
            _Float16 hh=(_Float16)h1v, hl=(_Float16)(h1v-(float)hh);
            Xh[woH1[g]] = hh; Xl[woH1[g]] = hl;
        }

        // ---- store heads(t-1) ----
        if (t > 0){
            size_t ob = ((size_t)(t-1)*BATCH + row0 + mr)*NOUT;
            #pragma unroll
            for (int e=0; e<4; ++e) out[ob + 4*q + e] = softplus_(H0[e]);
            #pragma unroll
            for (int e=0; e<4; ++e){
                int jo = 16 + 4*q + e;
                if (jo < NOUT) out[ob + jo] = softplus_(H1[e]);
            }
        }

        // ---- write feat(t+1) into feat region ----
        if (t+1 < TSTEPS){
            #pragma unroll
            for (int s=0; s<3; ++s) if (fV[s]){
                _Float16 h = (_Float16)fpre[s];
                Xh[fW[s]] = h; Xl[fW[s]] = (_Float16)(fpre[s] - (float)h);
            }
        }
        LDSFENCE();   // writes visible-in-order before next step's reads
    }

    // ---- epilogue: heads(191) on h0(191)|h1(191) ----
    {
        half8 xh0 = *(const half8*)(Xh + l*8);
        half8 xh1 = *(const half8*)(Xh + 512 + l*8);
        half8 xh2 = *(const half8*)(Xh + 1024 + l*8);
        f32x4 H0 = biash[0], H1 = biash[1];
        H0 = MFMA16(aHd[0][0], xh0, H0);  H1 = MFMA16(aHd[1][0], xh0, H1);
        H0 = MFMA16(aHd[0][1], xh1, H0);  H1 = MFMA16(aHd[1][1], xh1, H1);
        H0 = MFMA16(aHd[0][2], xh2, H0);  H1 = MFMA16(aHd[1][2], xh2, H1);
        size_t ob = ((size_t)(TSTEPS-1)*BATCH + row0 + mr)*NOUT;
        #pragma unroll
        for (int e=0; e<4; ++e) out[ob + 4*q + e] = softplus_(H0[e]);
        #pragma unroll
        for (int e=0; e<4; ++e){
            int jo = 16 + 4*q + e;
            if (jo < NOUT) out[ob + jo] = softplus_(H1[e]);
        }
    }
}

// ---------------------------------------------------------------------------
extern "C" void kernel_launch(void* const* d_in, const int* in_sizes, int n_in,
                              void* d_out, int out_size, void* d_ws, size_t ws_size,
                              hipStream_t stream)
{
    (void)in_sizes; (void)n_in; (void)out_size; (void)ws_size;
    const float* x_enc   = (const float*)d_in[0];
    const float* y_enc   = (const float*)d_in[3];
    const float* conv_w  = (const float*)d_in[5];
    const float* conv_b  = (const float*)d_in[6];
    const float* bn_w    = (const float*)d_in[7];
    const float* bn_b    = (const float*)d_in[8];
    const float* w_ih0   = (const float*)d_in[9];
    const float* w_hh0   = (const float*)d_in[10];
    const float* b0      = (const float*)d_in[11];
    const float* w_ih1   = (const float*)d_in[12];
    const float* w_hh1   = (const float*)d_in[13];
    const float* b1      = (const float*)d_in[14];
    const float* w_gamma = (const float*)d_in[15];
    const float* b_gamma = (const float*)d_in[16];
    const float* w_eta   = (const float*)d_in[17];
    const float* b_eta   = (const float*)d_in[18];

    float* out   = (float*)d_out;
    float* stats = (float*)d_ws;
    float* feat  = (float*)((char*)d_ws + FEAT_OFF);

    stats_kernel<<<TSTEPS, 256, 0, stream>>>(x_enc, y_enc, conv_w, conv_b, bn_w, bn_b, stats);
    feat_kernel<<<dim3(TSTEPS, BATCH/256), 256, 0, stream>>>(x_enc, y_enc, conv_w, conv_b, stats, feat);
    lstm_kernel<<<NBLK, NTH, 0, stream>>>(feat,
        w_ih0, w_hh0, b0, w_ih1, w_hh1, b1, w_gamma, b_gamma, w_eta, b_eta, out);
}

// Round 7
// 541.698 us; speedup vs baseline: 3.7089x; 3.7089x over previous
//
#include <hip/hip_runtime.h>
#include <cstdint>
#include <cstddef>

// ---------------- problem constants ----------------
#define TSTEPS 192
#define BATCH  4096
#define FRAW   20
#define FCONV  22
#define FCNN   11
#define HID    40
#define NOUT   21
#define ROWSPB 16
#define NTH    768              // 12 waves: 10 gate-tile waves + 2 head waves
#define NBLK   (BATCH/ROWSPB)   // 256 blocks = 1 block/CU (R5 lesson)

#define FEAT_OFF 4096           // ws: [0,1536) stats ; feat at byte offset 4096

typedef _Float16 half8 __attribute__((ext_vector_type(8)));
typedef float    f32x4 __attribute__((ext_vector_type(4)));
#define MFMA16(a,b,c) __builtin_amdgcn_mfma_f32_16x16x32_f16(a,b,c,0,0,0)

// LDS-only workgroup barrier: do NOT drain vmcnt (head waves have in-flight
// global stores every step; __syncthreads would stall all 12 waves on them).
#define WGBAR() do{ \
    __builtin_amdgcn_sched_barrier(0); \
    asm volatile("s_waitcnt lgkmcnt(0)" ::: "memory"); \
    __builtin_amdgcn_s_barrier(); \
    __builtin_amdgcn_sched_barrier(0); \
}while(0)

__device__ __forceinline__ float sigm_(float x){ return 1.f/(1.f+__expf(-x)); }
__device__ __forceinline__ float tanh_(float x){ float e=__expf(2.f*x); return 1.f-2.f/(e+1.f); }
__device__ __forceinline__ float softplus_(float x){ return fmaxf(x,0.f)+log1pf(__expf(-fabsf(x))); }

// fragment-layout offset (halves) of logical k, batch-row mr:
// [chunk=k>>5][q=(k>>3)&3][mr][i=k&7]; chunk stride 512, q stride 128
__device__ __forceinline__ int offk(int k, int mr){
    return ((k>>5)*4 + ((k>>3)&3))*128 + mr*8 + (k&7);
}

// -------- kernel 1: per-t BN affine params (unchanged) ----------------------
__global__ __launch_bounds__(256)
void stats_kernel(const float* __restrict__ x_enc, const float* __restrict__ y_enc,
                  const float* __restrict__ conv_w, const float* __restrict__ conv_b,
                  const float* __restrict__ bn_w, const float* __restrict__ bn_b,
                  float* __restrict__ stats)
{
    const int t = blockIdx.x;
    const float w0=conv_w[0], w1=conv_w[1], w2=conv_w[2], cb=conv_b[0];
    const float* src = (t < 96) ? (x_enc + (size_t)t*21) : (y_enc + (size_t)(t-96)*21);
    float s=0.f, ss=0.f;
    for (int b = threadIdx.x; b < BATCH; b += 256) {
        const float* xr = src + (size_t)b*2016;
        float xv[FRAW];
        #pragma unroll
        for (int f=0; f<FRAW; ++f) xv[f] = xr[f];
        #pragma unroll
        for (int i=0; i<FCONV; ++i) {
            float y = fmaf(w0, xv[(i+18)%20], fmaf(w1, xv[(i+19)%20], fmaf(w2, xv[i%20], cb)));
            s += y; ss = fmaf(y, y, ss);
        }
    }
    __shared__ float rs[256], rq[256];
    rs[threadIdx.x]=s; rq[threadIdx.x]=ss;
    __syncthreads();
    for (int o=128; o>0; o>>=1){
        if (threadIdx.x < o){ rs[threadIdx.x]+=rs[threadIdx.x+o]; rq[threadIdx.x]+=rq[threadIdx.x+o]; }
        __syncthreads();
    }
    if (threadIdx.x == 0){
        const float N = (float)(BATCH*FCONV);
        float mu  = rs[0]/N;
        float var = rq[0]/N - mu*mu;
        float A   = rsqrtf(var + 1e-5f) * bn_w[0];
        stats[2*t]   = A;
        stats[2*t+1] = bn_b[0] - mu*A;
    }
}

// -------- kernel 2: conv + BN + ELU + maxpool (unchanged) -------------------
__global__ __launch_bounds__(256)
void feat_kernel(const float* __restrict__ x_enc, const float* __restrict__ y_enc,
                 const float* __restrict__ conv_w, const float* __restrict__ conv_b,
                 const float* __restrict__ stats, float* __restrict__ feat)
{
    const int t = blockIdx.x;
    const int b = blockIdx.y*256 + threadIdx.x;
    const float w0=conv_w[0], w1=conv_w[1], w2=conv_w[2], cb=conv_b[0];
    const float A = stats[2*t], Bc = stats[2*t+1];
    const float* xr = ((t<96) ? (x_enc + (size_t)t*21) : (y_enc + (size_t)(t-96)*21)) + (size_t)b*2016;
    float xv[FRAW];
    #pragma unroll
    for (int f=0; f<FRAW; ++f) xv[f] = xr[f];
    float yv[FCONV];
    #pragma unroll
    for (int i=0; i<FCONV; ++i) {
        float y = fmaf(w0, xv[(i+18)%20], fmaf(w1, xv[(i+19)%20], fmaf(w2, xv[i%20], cb)));
        y = fmaf(y, A, Bc);
        yv[i] = (y > 0.f) ? y : expm1f(y);
    }
    float* fo = feat + ((size_t)t*BATCH + b)*FCNN;
    #pragma unroll
    for (int i=0; i<FCNN; ++i) {
        float m = (i==0) ? fmaxf(yv[0], yv[1])
                         : fmaxf(yv[2*i-1], fmaxf(yv[2*i], yv[2*i+1]));
        fo[i] = m;
    }
}

// -------- kernel 3: persistent MFMA LSTM, role-split waves ------------------
// 256 blocks x 768 thr (12 waves), 1 block/CU, 16 rows/block.
// Waves 0-9: gate wave g owns tile g (units 4g..4g+3); NO global traffic.
// Waves 10-11: heads(t-1) + feat prefetch/staging + all out stores.
// X0 (mod-2): K=64 frag buf [feat(0..10) | h0(11..50) | pad], 1024 halves/buf.
// B1 (mod-3): K=96 frag buf [h0(0..39) | h1(40..79) | pad], 1536 halves/buf.
// Race audit (step t; m=t%3, mn=(t+1)%3, mp=(t-1)%3; cur=t&1):
//  phase1 reads X0[cur]; writes h0(t)->X0[cur^1](k11-50) and B1[m](k0-39).
//  phase2 reads B1[m] (h0(t) k0-39 + h1(t-1) k40-79); writes h1(t)->B1[mn](k40-79).
//  heads(t-1) reads B1[mp](k0-39) [z0,z1(q=0)] and B1[m](k40-79) [z1(q>0),z2]:
//    vs phase1 write B1[m] k0-39: disjoint k. vs phase2 write B1[mn]: disjoint buf.
//  feat(t+1) -> X0[cur^1] k0-10 (after B1-barrier, before B2): disjoint from
//    phase1's k11-50 writes; X0[cur^1] not read until step t+1 phase1 (post-B2).
__global__ __launch_bounds__(NTH, 3)
void lstm_kernel(const float* __restrict__ feat,
                 const float* __restrict__ w_ih0, const float* __restrict__ w_hh0, const float* __restrict__ b0,
                 const float* __restrict__ w_ih1, const float* __restrict__ w_hh1, const float* __restrict__ b1,
                 const float* __restrict__ w_gamma, const float* __restrict__ b_gamma,
                 const float* __restrict__ w_eta,   const float* __restrict__ b_eta,
                 float* __restrict__ out)
{
    __shared__ __align__(16) _Float16 X0h[2*1024];
    __shared__ __align__(16) _Float16 X0l[2*1024];
    __shared__ __align__(16) _Float16 B1h[3*1536];
    __shared__ __align__(16) _Float16 B1l[3*1536];

    const int tid  = threadIdx.x;
    const int l    = tid & 63;
    const int wv   = tid >> 6;        // 0..9 gate, 10..11 head
    const int q    = l >> 4;
    const int mr   = l & 15;
    const int row0 = blockIdx.x * ROWSPB;
    const bool isGate = (wv < 10);

    // ---- zero LDS ----
    { uint32_t* z;
      z=(uint32_t*)X0h; for(int i=tid;i<1024;i+=NTH) z[i]=0u;
      z=(uint32_t*)X0l; for(int i=tid;i<1024;i+=NTH) z[i]=0u;
      z=(uint32_t*)B1h; for(int i=tid;i<2304;i+=NTH) z[i]=0u;
      z=(uint32_t*)B1l; for(int i=tid;i<2304;i+=NTH) z[i]=0u; }

    // =================== per-role setup ===================
    // gate-wave A fragments (hi/lo), biases, write offsets
    half8 a0h[2], a0l[2], a1h[3], a1l[3];
    f32x4 bias0={0,0,0,0}, bias1={0,0,0,0};
    int woX0=0, woB1a=0, woB1b=0;
    // head-wave A fragments (hi only), bias, staging maps
    half8 ahd[3];
    f32x4 biash={0,0,0,0};
    int fW0=0, fW1=0; bool fV0=false, fV1=false;
    const float* fG0 = feat; const float* fG1 = feat;

    if (isGate){
        const int uA = 4*wv + (mr >> 2);
        const int RA = (mr & 3)*40 + uA;       // torch row: gate-major
        #pragma unroll
        for (int c=0; c<2; ++c){
            #pragma unroll
            for (int i=0; i<8; ++i){
                int k = 32*c + 8*q + i;
                float v = (k<11) ? w_ih0[RA*11+k] : ((k<51) ? w_hh0[RA*40+k-11] : 0.f);
                _Float16 h = (_Float16)v;
                a0h[c][i]=h; a0l[c][i]=(_Float16)(v-(float)h);
            }
        }
        #pragma unroll
        for (int c=0; c<3; ++c){
            #pragma unroll
            for (int i=0; i<8; ++i){
                int k = 32*c + 8*q + i;        // B1 k-space: h0 at 0, h1 at 40
                float v = (k<40) ? w_ih1[RA*40+k]
                        : ((k<80) ? w_hh1[RA*40+k-40] : 0.f);
                _Float16 h = (_Float16)v;
                a1h[c][i]=h; a1l[c][i]=(_Float16)(v-(float)h);
            }
        }
        const int u = 4*wv + q;
        bias0[0]=b0[u]; bias0[1]=b0[40+u]; bias0[2]=b0[80+u]; bias0[3]=b0[120+u];
        bias1[0]=b1[u]; bias1[1]=b1[40+u]; bias1[2]=b1[80+u]; bias1[3]=b1[120+u];
        woX0  = offk(11+u, mr);
        woB1a = offk(u, mr);
        woB1b = offk(40+u, mr);
    } else {
        const int hw = wv - 10;                // 0 or 1
        const int jo = 16*hw + mr;             // head A row
        #pragma unroll
        for (int c=0; c<3; ++c){
            #pragma unroll
            for (int i=0; i<8; ++i){
                int k = 32*c + 8*q + i;        // B1 k-space
                float v = 0.f;
                if (jo < NOUT && k < 80){
                    int col = (k<40) ? 2*k : 2*(k-40)+1;   // hp interleave folded
                    v = (jo==0) ? w_gamma[col] : w_eta[(jo-1)*80 + col];
                }
                ahd[c][i] = (_Float16)v;
            }
        }
        #pragma unroll
        for (int e=0; e<4; ++e){
            int j2 = 16*hw + 4*q + e;
            biash[e] = (j2 < NOUT) ? ((j2==0) ? b_gamma[0] : b_eta[j2-1]) : 0.f;
        }
        // feat staging: 176 elems over 128 head lanes (2 slots)
        const int hl = tid - 640;              // 0..127
        int i0 = hl, i1 = hl + 128;
        fV0 = (i0 < ROWSPB*FCNN); fV1 = (i1 < ROWSPB*FCNN);
        { int r = i0/FCNN, f = i0 - FCNN*r; r &= 15; fW0 = offk(f, r);
          fG0 = feat + (size_t)(row0 + r)*FCNN + f; }
        { int r = (fV1? i1 : 0)/FCNN, f = (fV1? i1 : 0) - FCNN*((fV1? i1 : 0)/FCNN);
          r &= 15; fW1 = offk(f, r);
          fG1 = feat + (size_t)(row0 + r)*FCNN + f; }
    }

    __syncthreads();    // zero-init visible
    if (!isGate){       // stage feat(0) into X0[0]
        if (fV0){ float v=fG0[0]; _Float16 h=(_Float16)v; X0h[fW0]=h; X0l[fW0]=(_Float16)(v-(float)h); }
        if (fV1){ float v=fG1[0]; _Float16 h=(_Float16)v; X0h[fW1]=h; X0l[fW1]=(_Float16)(v-(float)h); }
    }
    __syncthreads();

    float c0=0.f, c1=0.f;
    int cur=0, m=0, mp=0;
    const size_t featStep = (size_t)BATCH*FCNN;

    for (int t=0; t<TSTEPS; ++t){
        const int mn = (m==2) ? 0 : m+1;

        if (isGate){
            // ---------- phase 1: layer0, K=64, 2 split chains ----------
            const _Float16* xb = X0h + cur*1024 + l*8;
            const _Float16* xlb= X0l + cur*1024 + l*8;
            half8 xh0 = *(const half8*)(xb);
            half8 xh1 = *(const half8*)(xb + 512);
            half8 xl0 = *(const half8*)(xlb);
            half8 xl1 = *(const half8*)(xlb + 512);
            f32x4 cA = bias0;
            cA = MFMA16(a0h[0], xh0, cA);
            cA = MFMA16(a0l[0], xh0, cA);
            cA = MFMA16(a0h[0], xl0, cA);
            f32x4 cB = {0.f,0.f,0.f,0.f};
            cB = MFMA16(a0h[1], xh1, cB);
            cB = MFMA16(a0l[1], xh1, cB);
            cB = MFMA16(a0h[1], xl1, cB);
            f32x4 acc = cA + cB;
            {
                float ig=sigm_(acc[0]), fg=sigm_(acc[1]), gv=tanh_(acc[2]), og=sigm_(acc[3]);
                c0 = fmaf(fg, c0, ig*gv);
                float h0v = og * tanh_(c0);
                _Float16 hh=(_Float16)h0v, hl2=(_Float16)(h0v-(float)hh);
                int o1 = (cur^1)*1024 + woX0;
                int o2 = m*1536 + woB1a;
                X0h[o1]=hh; X0l[o1]=hl2;
                B1h[o2]=hh; B1l[o2]=hl2;
            }
        } else {
            // ---------- head waves: prefetch feat(t+1), heads(t-1) ----------
            float fp0=0.f, fp1=0.f;
            if (t+1 < TSTEPS){
                if (fV0) fp0 = fG0[(size_t)(t+1)*featStep];
                if (fV1) fp1 = fG1[(size_t)(t+1)*featStep];
            }
            if (t > 0){
                const _Float16* ba = B1h + mp*1536 + l*8;
                const _Float16* bb = B1h + m*1536  + l*8;
                half8 z0 = *(const half8*)(ba);
                half8 z1 = *(const half8*)(((q==0) ? ba : bb) + 512);
                half8 z2 = *(const half8*)(bb + 1024);
                f32x4 H = biash;
                H = MFMA16(ahd[0], z0, H);
                H = MFMA16(ahd[1], z1, H);
                H = MFMA16(ahd[2], z2, H);
                float* op = out + ((size_t)(t-1)*BATCH + row0 + mr)*NOUT;
                const int jb = 16*(wv-10) + 4*q;
                #pragma unroll
                for (int e=0; e<4; ++e){
                    int j2 = jb + e;
                    if (j2 < NOUT) op[j2] = softplus_(H[e]);
                }
            }
            // stash prefetch in LDS AFTER barrier (see below) — carry in regs:
            // (fall through; fp0/fp1 written post-B1)
            if (t+1 < TSTEPS){
                // defer actual ds_write until after WGBAR below via branchless
                // trick: we simply do it after the barrier in this same iter.
                // store in volatile-free locals (kept live across barrier)
                // -- handled below --
            }
            // keep fp0/fp1 alive:
            asm volatile("" :: "v"(fp0), "v"(fp1));
            // B1 barrier happens below (common path); feat write after it.
            // To pass values across the structured code, recompute path:
            // we re-enter the write in the common section via these regs.
            // (implemented by writing them right after WGBAR in head branch)
            // -- see post-barrier head block --
            // NOTE: fp0/fp1 used below.
            if (false) { (void)fp0; (void)fp1; }
            // save to locals outside the if-scope:
            goto head_b1;   // structured below
            head_b1:;
            WGBAR();        // ---- B1 barrier (head waves) ----
            if (t+1 < TSTEPS){
                int o1 = (cur^1)*1024 + fW0;
                if (fV0){ _Float16 h=(_Float16)fp0; X0h[o1]=h; X0l[o1]=(_Float16)(fp0-(float)h); }
                int o2 = (cur^1)*1024 + fW1;
                if (fV1){ _Float16 h=(_Float16)fp1; X0h[o2]=h; X0l[o2]=(_Float16)(fp1-(float)h); }
            }
            WGBAR();        // ---- B2 barrier (head waves) ----
            mp = m; m = mn; cur ^= 1;
            continue;       // next t
        }

        WGBAR();            // ---- B1 barrier (gate waves) ----

        // ---------- phase 2: layer1, K=96, 3 split chains ----------
        {
            const _Float16* yb = B1h + m*1536 + l*8;
            const _Float16* ylb= B1l + m*1536 + l*8;
            half8 yh0 = *(const half8*)(yb);
            half8 yh1 = *(const half8*)(yb + 512);
            half8 yh2 = *(const half8*)(yb + 1024);
            half8 yl0 = *(const half8*)(ylb);
            half8 yl1 = *(const half8*)(ylb + 512);
            half8 yl2 = *(const half8*)(ylb + 1024);
            f32x4 cA = bias1;
            cA = MFMA16(a1h[0], yh0, cA);
            cA = MFMA16(a1l[0], yh0, cA);
            cA = MFMA16(a1h[0], yl0, cA);
            f32x4 cB = {0.f,0.f,0.f,0.f};
            cB = MFMA16(a1h[1], yh1, cB);
            cB = MFMA16(a1l[1], yh1, cB);
            cB = MFMA16(a1h[1], yl1, cB);
            f32x4 cC = {0.f,0.f,0.f,0.f};
            cC = MFMA16(a1h[2], yh2, cC);
            cC = MFMA16(a1l[2], yh2, cC);
            cC = MFMA16(a1h[2], yl2, cC);
            f32x4 acc = (cA + cB) + cC;
            float ig=sigm_(acc[0]), fg=sigm_(acc[1]), gv=tanh_(acc[2]), og=sigm_(acc[3]);
            c1 = fmaf(fg, c1, ig*gv);
            float h1v = og * tanh_(c1);
            _Float16 hh=(_Float16)h1v, hl2=(_Float16)(h1v-(float)hh);
            int ob = mn*1536 + woB1b;
            B1h[ob]=hh; B1l[ob]=hl2;
        }

        WGBAR();            // ---- B2 barrier (gate waves) ----
        mp = m; m = mn; cur ^= 1;
    }

    // ---- epilogue: heads(191); h0(191) in B1[mp], h1(191) in B1[m] ----
    if (!isGate){
        const _Float16* ba = B1h + mp*1536 + l*8;
        const _Float16* bb = B1h + m*1536  + l*8;
        half8 z0 = *(const half8*)(ba);
        half8 z1 = *(const half8*)(((q==0) ? ba : bb) + 512);
        half8 z2 = *(const half8*)(bb + 1024);
        f32x4 H = biash;
        H = MFMA16(ahd[0], z0, H);
        H = MFMA16(ahd[1], z1, H);
        H = MFMA16(ahd[2], z2, H);
        float* op = out + ((size_t)(TSTEPS-1)*BATCH + row0 + mr)*NOUT;
        const int jb = 16*(wv-10) + 4*q;
        #pragma unroll
        for (int e=0; e<4; ++e){
            int j2 = jb + e;
            if (j2 < NOUT) op[j2] = softplus_(H[e]);
        }
    }
}

// ---------------------------------------------------------------------------
extern "C" void kernel_launch(void* const* d_in, const int* in_sizes, int n_in,
                              void* d_out, int out_size, void* d_ws, size_t ws_size,
                              hipStream_t stream)
{
    (void)in_sizes; (void)n_in; (void)out_size; (void)ws_size;
    const float* x_enc   = (const float*)d_in[0];
    const float* y_enc   = (const float*)d_in[3];
    const float* conv_w  = (const float*)d_in[5];
    const float* conv_b  = (const float*)d_in[6];
    const float* bn_w    = (const float*)d_in[7];
    const float* bn_b    = (const float*)d_in[8];
    const float* w_ih0   = (const float*)d_in[9];
    const float* w_hh0   = (const float*)d_in[10];
    const float* b0      = (const float*)d_in[11];
    const float* w_ih1   = (const float*)d_in[12];
    const float* w_hh1   = (const float*)d_in[13];
    const float* b1      = (const float*)d_in[14];
    const float* w_gamma = (const float*)d_in[15];
    const float* b_gamma = (const float*)d_in[16];
    const float* w_eta   = (const float*)d_in[17];
    const float* b_eta   = (const float*)d_in[18];

    float* out   = (float*)d_out;
    float* stats = (float*)d_ws;
    float* feat  = (float*)((char*)d_ws + FEAT_OFF);

    stats_kernel<<<TSTEPS, 256, 0, stream>>>(x_enc, y_enc, conv_w, conv_b, bn_w, bn_b, stats);
    feat_kernel<<<dim3(TSTEPS, BATCH/256), 256, 0, stream>>>(x_enc, y_enc, conv_w, conv_b, stats, feat);
    lstm_kernel<<<NBLK, NTH, 0, stream>>>(feat,
        w_ih0, w_hh0, b0, w_ih1, w_hh1, b1, w_gamma, b_gamma, w_eta, b_eta, out);
}

// Round 8
// 524.454 us; speedup vs baseline: 3.8308x; 1.0329x over previous
//
#include <hip/hip_runtime.h>
#include <cstdint>
#include <cstddef>

// ---------------- problem constants ----------------
#define TSTEPS 192
#define BATCH  4096
#define FRAW   20
#define FCONV  22
#define FCNN   11
#define HID    40
#define NOUT   21
#define ROWSPB 16
#define NTH    768              // 12 waves: 5 L0 + 5 L1 + 2 head/feat
#define NBLK   (BATCH/ROWSPB)   // 256 blocks = 1 block/CU

#define FEAT_OFF 4096           // ws: [0,1536) stats ; feat at byte offset 4096

typedef _Float16 half8 __attribute__((ext_vector_type(8)));
typedef float    f32x4 __attribute__((ext_vector_type(4)));
#define MFMA16(a,b,c) __builtin_amdgcn_mfma_f32_16x16x32_f16(a,b,c,0,0,0)

// LDS-only workgroup barrier (do not drain vmcnt: head waves keep global
// loads/stores in flight across it).
#define WGBAR() do{ \
    __builtin_amdgcn_sched_barrier(0); \
    asm volatile("s_waitcnt lgkmcnt(0)" ::: "memory"); \
    __builtin_amdgcn_s_barrier(); \
    __builtin_amdgcn_sched_barrier(0); \
}while(0)

__device__ __forceinline__ float sigm_(float x){ return 1.f/(1.f+__expf(-x)); }
__device__ __forceinline__ float tanh_(float x){ float e=__expf(2.f*x); return 1.f-2.f/(e+1.f); }
__device__ __forceinline__ float softplus_(float x){ return fmaxf(x,0.f)+log1pf(__expf(-fabsf(x))); }

// fragment-layout offset (halves) of logical k, batch-row mr:
// [chunk=k>>5][q=(k>>3)&3][mr][i=k&7]; chunk stride 512, q stride 128
__device__ __forceinline__ int offk(int k, int mr){
    return ((k>>5)*4 + ((k>>3)&3))*128 + mr*8 + (k&7);
}

// -------- kernel 1: per-t BN affine params (unchanged) ----------------------
__global__ __launch_bounds__(256)
void stats_kernel(const float* __restrict__ x_enc, const float* __restrict__ y_enc,
                  const float* __restrict__ conv_w, const float* __restrict__ conv_b,
                  const float* __restrict__ bn_w, const float* __restrict__ bn_b,
                  float* __restrict__ stats)
{
    const int t = blockIdx.x;
    const float w0=conv_w[0], w1=conv_w[1], w2=conv_w[2], cb=conv_b[0];
    const float* src = (t < 96) ? (x_enc + (size_t)t*21) : (y_enc + (size_t)(t-96)*21);
    float s=0.f, ss=0.f;
    for (int b = threadIdx.x; b < BATCH; b += 256) {
        const float* xr = src + (size_t)b*2016;
        float xv[FRAW];
        #pragma unroll
        for (int f=0; f<FRAW; ++f) xv[f] = xr[f];
        #pragma unroll
        for (int i=0; i<FCONV; ++i) {
            float y = fmaf(w0, xv[(i+18)%20], fmaf(w1, xv[(i+19)%20], fmaf(w2, xv[i%20], cb)));
            s += y; ss = fmaf(y, y, ss);
        }
    }
    __shared__ float rs[256], rq[256];
    rs[threadIdx.x]=s; rq[threadIdx.x]=ss;
    __syncthreads();
    for (int o=128; o>0; o>>=1){
        if (threadIdx.x < o){ rs[threadIdx.x]+=rs[threadIdx.x+o]; rq[threadIdx.x]+=rq[threadIdx.x+o]; }
        __syncthreads();
    }
    if (threadIdx.x == 0){
        const float N = (float)(BATCH*FCONV);
        float mu  = rs[0]/N;
        float var = rq[0]/N - mu*mu;
        float A   = rsqrtf(var + 1e-5f) * bn_w[0];
        stats[2*t]   = A;
        stats[2*t+1] = bn_b[0] - mu*A;
    }
}

// -------- kernel 2: conv + BN + ELU + maxpool (unchanged) -------------------
__global__ __launch_bounds__(256)
void feat_kernel(const float* __restrict__ x_enc, const float* __restrict__ y_enc,
                 const float* __restrict__ conv_w, const float* __restrict__ conv_b,
                 const float* __restrict__ stats, float* __restrict__ feat)
{
    const int t = blockIdx.x;
    const int b = blockIdx.y*256 + threadIdx.x;
    const float w0=conv_w[0], w1=conv_w[1], w2=conv_w[2], cb=conv_b[0];
    const float A = stats[2*t], Bc = stats[2*t+1];
    const float* xr = ((t<96) ? (x_enc + (size_t)t*21) : (y_enc + (size_t)(t-96)*21)) + (size_t)b*2016;
    float xv[FRAW];
    #pragma unroll
    for (int f=0; f<FRAW; ++f) xv[f] = xr[f];
    float yv[FCONV];
    #pragma unroll
    for (int i=0; i<FCONV; ++i) {
        float y = fmaf(w0, xv[(i+18)%20], fmaf(w1, xv[(i+19)%20], fmaf(w2, xv[i%20], cb)));
        y = fmaf(y, A, Bc);
        yv[i] = (y > 0.f) ? y : expm1f(y);
    }
    float* fo = feat + ((size_t)t*BATCH + b)*FCNN;
    #pragma unroll
    for (int i=0; i<FCNN; ++i) {
        float m = (i==0) ? fmaxf(yv[0], yv[1])
                         : fmaxf(yv[2*i-1], fmaxf(yv[2*i], yv[2*i+1]));
        fo[i] = m;
    }
}

// -------- kernel 3: layer-pipelined MFMA LSTM, ONE barrier per step ---------
// 256 blocks x 768 thr (12 waves), 1 block/CU, 16 rows/block.
//  waves 0-4 : L0(i)  = h0(i)   from {feat(i), h0(i-1)}       (2 tiles each)
//  waves 5-9 : L1(i-1)= h1(i-1) from {h0(i-1), h1(i-2)}       (2 tiles each)
//  waves 10-11: heads out(i-2) from {h0(i-2), h1(i-2)} + feat staging/stores
// X0 (mod-2, K=64): [feat(0..10) | h0(11..50) | pad], 1024 halves/buf.
// B1 (mod-3, K=96): [h0(0..39)   | h1(40..79) | pad], 1536 halves/buf.
// Iter i indices: a=i&1, c=i%3, cp=(i-1)%3, cn=(i+1)%3.
// Race audit (all separated by the single end-of-iter barrier):
//  readers at iter i: L0 <- X0[a]; L1 <- B1[c]; heads <- B1[cp] (h0-region)
//    and B1[c] (h1-region); all these were last written at iters <= i-1.
//  writers at iter i: L0 -> X0[a^1] k11-50, B1[cn] k0-39;
//    L1 -> B1[cn] k40-79; feat -> X0[a^1] k0-10.   Distinct from all
//    same-iter read buffers (a^1 != a; cn != c,cp); write-write disjoint k.
//  B1[cn]=B1[cp(i+... ] next written at iter i+3, re-read at i+1/i+2 only.
__global__ __launch_bounds__(NTH, 3)
void lstm_kernel(const float* __restrict__ feat,
                 const float* __restrict__ w_ih0, const float* __restrict__ w_hh0, const float* __restrict__ b0,
                 const float* __restrict__ w_ih1, const float* __restrict__ w_hh1, const float* __restrict__ b1,
                 const float* __restrict__ w_gamma, const float* __restrict__ b_gamma,
                 const float* __restrict__ w_eta,   const float* __restrict__ b_eta,
                 float* __restrict__ out)
{
    __shared__ __align__(16) _Float16 X0h[2*1024];
    __shared__ __align__(16) _Float16 X0l[2*1024];
    __shared__ __align__(16) _Float16 B1h[3*1536];
    __shared__ __align__(16) _Float16 B1l[3*1536];

    const int tid  = threadIdx.x;
    const int l    = tid & 63;
    const int wv   = tid >> 6;
    const int q    = l >> 4;
    const int mr   = l & 15;
    const int row0 = blockIdx.x * ROWSPB;
    const bool isL0 = (wv < 5);
    const bool isL1 = (wv >= 5 && wv < 10);

    // ---- zero LDS ----
    { uint32_t* z;
      z=(uint32_t*)X0h; for(int i=tid;i<1024;i+=NTH) z[i]=0u;
      z=(uint32_t*)X0l; for(int i=tid;i<1024;i+=NTH) z[i]=0u;
      z=(uint32_t*)B1h; for(int i=tid;i<2304;i+=NTH) z[i]=0u;
      z=(uint32_t*)B1l; for(int i=tid;i<2304;i+=NTH) z[i]=0u; }

    // =================== per-role setup ===================
    half8 a0h[2][2], a0l[2][2];            // L0: [tile][chunk]
    half8 a1h[2][3], a1l[2][3];            // L1: [tile][chunk]
    half8 ahd[3];                          // heads (hi only)
    f32x4 bias0[2]={{0,0,0,0},{0,0,0,0}}, bias1[2]={{0,0,0,0},{0,0,0,0}};
    f32x4 biash={0,0,0,0};
    int woX0[2]={0,0}, woB1[2]={0,0}, woH1[2]={0,0};
    int fW0=0, fW1=0; bool fV0=false, fV1=false;
    const float* fG0 = feat; const float* fG1 = feat;

    if (isL0){
        #pragma unroll
        for (int g=0; g<2; ++g){
            const int uA = 4*(2*wv+g) + (mr >> 2);
            const int RA = (mr & 3)*40 + uA;           // torch row: gate-major
            #pragma unroll
            for (int cchunk=0; cchunk<2; ++cchunk){
                #pragma unroll
                for (int ii=0; ii<8; ++ii){
                    int k = 32*cchunk + 8*q + ii;
                    float v = (k<11) ? w_ih0[RA*11+k] : ((k<51) ? w_hh0[RA*40+k-11] : 0.f);
                    _Float16 h = (_Float16)v;
                    a0h[g][cchunk][ii]=h; a0l[g][cchunk][ii]=(_Float16)(v-(float)h);
                }
            }
            const int u = 4*(2*wv+g) + q;
            bias0[g][0]=b0[u]; bias0[g][1]=b0[40+u]; bias0[g][2]=b0[80+u]; bias0[g][3]=b0[120+u];
            woX0[g] = offk(11+u, mr);
            woB1[g] = offk(u, mr);
        }
    } else if (isL1){
        const int wl = wv - 5;
        #pragma unroll
        for (int g=0; g<2; ++g){
            const int uA = 4*(2*wl+g) + (mr >> 2);
            const int RA = (mr & 3)*40 + uA;
            #pragma unroll
            for (int cchunk=0; cchunk<3; ++cchunk){
                #pragma unroll
                for (int ii=0; ii<8; ++ii){
                    int k = 32*cchunk + 8*q + ii;      // B1 k-space: h0@0, h1@40
                    float v = (k<40) ? w_ih1[RA*40+k]
                            : ((k<80) ? w_hh1[RA*40+k-40] : 0.f);
                    _Float16 h = (_Float16)v;
                    a1h[g][cchunk][ii]=h; a1l[g][cchunk][ii]=(_Float16)(v-(float)h);
                }
            }
            const int u = 4*(2*wl+g) + q;
            bias1[g][0]=b1[u]; bias1[g][1]=b1[40+u]; bias1[g][2]=b1[80+u]; bias1[g][3]=b1[120+u];
            woH1[g] = offk(40+u, mr);
        }
    } else {
        const int hw = wv - 10;                        // 0 or 1
        const int jo = 16*hw + mr;
        #pragma unroll
        for (int cchunk=0; cchunk<3; ++cchunk){
            #pragma unroll
            for (int ii=0; ii<8; ++ii){
                int k = 32*cchunk + 8*q + ii;
                float v = 0.f;
                if (jo < NOUT && k < 80){
                    int col = (k<40) ? 2*k : 2*(k-40)+1;   // hp interleave folded
                    v = (jo==0) ? w_gamma[col] : w_eta[(jo-1)*80 + col];
                }
                ahd[cchunk][ii] = (_Float16)v;
            }
        }
        #pragma unroll
        for (int e=0; e<4; ++e){
            int j2 = 16*hw + 4*q + e;
            biash[e] = (j2 < NOUT) ? ((j2==0) ? b_gamma[0] : b_eta[j2-1]) : 0.f;
        }
        const int hl = tid - 640;                      // 0..127
        int i0 = hl, i1 = hl + 128;
        fV0 = (i0 < ROWSPB*FCNN); fV1 = (i1 < ROWSPB*FCNN);
        { int r = i0/FCNN, f = i0 - FCNN*r; r &= 15; fW0 = offk(f, r);
          fG0 = feat + (size_t)(row0 + r)*FCNN + f; }
        { int ix = fV1 ? i1 : 0;
          int r = ix/FCNN, f = ix - FCNN*(ix/FCNN); r &= 15; fW1 = offk(f, r);
          fG1 = feat + (size_t)(row0 + r)*FCNN + f; }
    }

    __syncthreads();    // zero-init visible before feat(0) staging
    float fA0=0.f, fA1=0.f, fB0=0.f, fB1=0.f;
    if (!isL0 && !isL1){
        if (fV0){ float v=fG0[0]; _Float16 h=(_Float16)v; X0h[fW0]=h; X0l[fW0]=(_Float16)(v-(float)h); }
        if (fV1){ float v=fG1[0]; _Float16 h=(_Float16)v; X0h[fW1]=h; X0l[fW1]=(_Float16)(v-(float)h); }
        // preload feat(1) -> slot B (slot parity: slot (t&1) holds feat(t))
        const size_t fs = (size_t)BATCH*FCNN;
        if (fV0) fB0 = fG0[fs];
        if (fV1) fB1 = fG1[fs];
    }
    __syncthreads();

    float c0[2]={0.f,0.f}, c1[2]={0.f,0.f};
    int a=0, c=0, cp=2, cn=1;
    const size_t featStep = (size_t)BATCH*FCNN;

    for (int i=0; i<TSTEPS+2; ++i){     // 194 iterations, ONE barrier each
        if (isL0){
            if (i < TSTEPS){
                const _Float16* xb  = X0h + a*1024 + l*8;
                const _Float16* xlb = X0l + a*1024 + l*8;
                half8 xh0 = *(const half8*)(xb);
                half8 xh1 = *(const half8*)(xb + 512);
                half8 xl0 = *(const half8*)(xlb);
                half8 xl1 = *(const half8*)(xlb + 512);
                #pragma unroll
                for (int g=0; g<2; ++g){
                    f32x4 cA = bias0[g];
                    cA = MFMA16(a0h[g][0], xh0, cA);
                    cA = MFMA16(a0l[g][0], xh0, cA);
                    cA = MFMA16(a0h[g][0], xl0, cA);
                    f32x4 cB = {0.f,0.f,0.f,0.f};
                    cB = MFMA16(a0h[g][1], xh1, cB);
                    cB = MFMA16(a0l[g][1], xh1, cB);
                    cB = MFMA16(a0h[g][1], xl1, cB);
                    f32x4 acc = cA + cB;
                    float ig=sigm_(acc[0]), fg=sigm_(acc[1]), gv=tanh_(acc[2]), og=sigm_(acc[3]);
                    c0[g] = fmaf(fg, c0[g], ig*gv);
                    float h0v = og * tanh_(c0[g]);
                    _Float16 hh=(_Float16)h0v, hl2=(_Float16)(h0v-(float)hh);
                    int o1 = (a^1)*1024 + woX0[g];
                    int o2 = cn*1536 + woB1[g];
                    X0h[o1]=hh; X0l[o1]=hl2;
                    B1h[o2]=hh; B1l[o2]=hl2;
                }
            }
        } else if (isL1){
            if (i >= 1 && i <= TSTEPS){
                const _Float16* yb  = B1h + c*1536 + l*8;
                const _Float16* ylb = B1l + c*1536 + l*8;
                half8 yh0 = *(const half8*)(yb);
                half8 yh1 = *(const half8*)(yb + 512);
                half8 yh2 = *(const half8*)(yb + 1024);
                half8 yl0 = *(const half8*)(ylb);
                half8 yl1 = *(const half8*)(ylb + 512);
                half8 yl2 = *(const half8*)(ylb + 1024);
                #pragma unroll
                for (int g=0; g<2; ++g){
                    f32x4 cA = bias1[g];
                    cA = MFMA16(a1h[g][0], yh0, cA);
                    cA = MFMA16(a1l[g][0], yh0, cA);
                    cA = MFMA16(a1h[g][0], yl0, cA);
                    f32x4 cB = {0.f,0.f,0.f,0.f};
                    cB = MFMA16(a1h[g][1], yh1, cB);
                    cB = MFMA16(a1l[g][1], yh1, cB);
                    cB = MFMA16(a1h[g][1], yl1, cB);
                    f32x4 cC = {0.f,0.f,0.f,0.f};
                    cC = MFMA16(a1h[g][2], yh2, cC);
                    cC = MFMA16(a1l[g][2], yh2, cC);
                    cC = MFMA16(a1h[g][2], yl2, cC);
                    f32x4 acc = (cA + cB) + cC;
                    float ig=sigm_(acc[0]), fg=sigm_(acc[1]), gv=tanh_(acc[2]), og=sigm_(acc[3]);
                    c1[g] = fmaf(fg, c1[g], ig*gv);
                    float h1v = og * tanh_(c1[g]);
                    _Float16 hh=(_Float16)h1v, hl2=(_Float16)(h1v-(float)hh);
                    int ob = cn*1536 + woH1[g];
                    B1h[ob]=hh; B1l[ob]=hl2;
                }
            }
        } else {
            // ---- feat staging: write feat(i+1) into X0[a^1] ----
            if (i < TSTEPS-1){
                float v0, v1;
                if ((i&1)==0){ v0=fB0; v1=fB1; } else { v0=fA0; v1=fA1; }
                int ob = (a^1)*1024;
                if (fV0){ _Float16 h=(_Float16)v0; X0h[ob+fW0]=h; X0l[ob+fW0]=(_Float16)(v0-(float)h); }
                if (fV1){ _Float16 h=(_Float16)v1; X0h[ob+fW1]=h; X0l[ob+fW1]=(_Float16)(v1-(float)h); }
            }
            // ---- prefetch feat(i+2) into the opposite slot ----
            if (i+2 < TSTEPS){
                size_t o = (size_t)(i+2)*featStep;
                if ((i&1)==0){ if(fV0) fA0=fG0[o]; if(fV1) fA1=fG1[o]; }
                else         { if(fV0) fB0=fG0[o]; if(fV1) fB1=fG1[o]; }
            }
            // ---- heads: out(i-2) ----
            if (i >= 2){
                const _Float16* ba = B1h + cp*1536 + l*8;   // h0(i-2)
                const _Float16* bb = B1h + c*1536  + l*8;   // h1(i-2)
                half8 z0 = *(const half8*)(ba);
                half8 z1 = *(const half8*)(((q==0) ? ba : bb) + 512);
                half8 z2 = *(const half8*)(bb + 1024);
                f32x4 H = biash;
                H = MFMA16(ahd[0], z0, H);
                H = MFMA16(ahd[1], z1, H);
                H = MFMA16(ahd[2], z2, H);
                float* op = out + ((size_t)(i-2)*BATCH + row0 + mr)*NOUT;
                const int jb = 16*(wv-10) + 4*q;
                #pragma unroll
                for (int e=0; e<4; ++e){
                    int j2 = jb + e;
                    if (j2 < NOUT) op[j2] = softplus_(H[e]);
                }
            }
        }

        WGBAR();        // the single per-iteration barrier
        a ^= 1;
        cp = c; c = cn; cn = (cn==2) ? 0 : cn+1;
    }
}

// ---------------------------------------------------------------------------
extern "C" void kernel_launch(void* const* d_in, const int* in_sizes, int n_in,
                              void* d_out, int out_size, void* d_ws, size_t ws_size,
                              hipStream_t stream)
{
    (void)in_sizes; (void)n_in; (void)out_size; (void)ws_size;
    const float* x_enc   = (const float*)d_in[0];
    const float* y_enc   = (const float*)d_in[3];
    const float* conv_w  = (const float*)d_in[5];
    const float* conv_b  = (const float*)d_in[6];
    const float* bn_w    = (const float*)d_in[7];
    const float* bn_b    = (const float*)d_in[8];
    const float* w_ih0   = (const float*)d_in[9];
    const float* w_hh0   = (const float*)d_in[10];
    const float* b0      = (const float*)d_in[11];
    const float* w_ih1   = (const float*)d_in[12];
    const float* w_hh1   = (const float*)d_in[13];
    const float* b1      = (const float*)d_in[14];
    const float* w_gamma = (const float*)d_in[15];
    const float* b_gamma = (const float*)d_in[16];
    const float* w_eta   = (const float*)d_in[17];
    const float* b_eta   = (const float*)d_in[18];

    float* out   = (float*)d_out;
    float* stats = (float*)d_ws;
    float* feat  = (float*)((char*)d_ws + FEAT_OFF);

    stats_kernel<<<TSTEPS, 256, 0, stream>>>(x_enc, y_enc, conv_w, conv_b, bn_w, bn_b, stats);
    feat_kernel<<<dim3(TSTEPS, BATCH/256), 256, 0, stream>>>(x_enc, y_enc, conv_w, conv_b, stats, feat);
    lstm_kernel<<<NBLK, NTH, 0, stream>>>(feat,
        w_ih0, w_hh0, b0, w_ih1, w_hh1, b1, w_gamma, b_gamma, w_eta, b_eta, out);
}

// Round 10
// 424.776 us; speedup vs baseline: 4.7298x; 1.2347x over previous
//
#include <hip/hip_runtime.h>
#include <cstdint>
#include <cstddef>

// ---------------- problem constants ----------------
#define TSTEPS 192
#define BATCH  4096
#define FRAW   20
#define FCONV  22
#define FCNN   11
#define HID    40
#define NOUT   21
#define ROWSPB 16
#define NTH    768              // 12 waves: 5 L0 + 5 L1 + 2 head/feat
#define NBLK   (BATCH/ROWSPB)   // 256 blocks = 1 block/CU

#define FEAT_OFF 4096           // ws: [0,1536) stats ; feat at byte offset 4096

typedef _Float16 half8 __attribute__((ext_vector_type(8)));
typedef float    f32x4 __attribute__((ext_vector_type(4)));
#define MFMA16(a,b,c) __builtin_amdgcn_mfma_f32_16x16x32_f16(a,b,c,0,0,0)

// LDS-only workgroup barrier (do not drain vmcnt: head waves keep global
// loads/stores in flight across it).
#define WGBAR() do{ \
    __builtin_amdgcn_sched_barrier(0); \
    asm volatile("s_waitcnt lgkmcnt(0)" ::: "memory"); \
    __builtin_amdgcn_s_barrier(); \
    __builtin_amdgcn_sched_barrier(0); \
}while(0)

__device__ __forceinline__ float sigm_(float x){ return 1.f/(1.f+__expf(-x)); }
__device__ __forceinline__ float tanh_(float x){ float e=__expf(2.f*x); return 1.f-2.f/(e+1.f); }
__device__ __forceinline__ float softplus_(float x){ return fmaxf(x,0.f)+log1pf(__expf(-fabsf(x))); }

// fragment-layout offset (halves) of logical k, batch-row mr:
// [chunk=k>>5][q=(k>>3)&3][mr][i=k&7]; chunk stride 512, q stride 128
__device__ __forceinline__ int offk(int k, int mr){
    return ((k>>5)*4 + ((k>>3)&3))*128 + mr*8 + (k&7);
}

// -------- kernel 1: per-t BN affine params (unchanged) ----------------------
__global__ __launch_bounds__(256)
void stats_kernel(const float* __restrict__ x_enc, const float* __restrict__ y_enc,
                  const float* __restrict__ conv_w, const float* __restrict__ conv_b,
                  const float* __restrict__ bn_w, const float* __restrict__ bn_b,
                  float* __restrict__ stats)
{
    const int t = blockIdx.x;
    const float w0=conv_w[0], w1=conv_w[1], w2=conv_w[2], cb=conv_b[0];
    const float* src = (t < 96) ? (x_enc + (size_t)t*21) : (y_enc + (size_t)(t-96)*21);
    float s=0.f, ss=0.f;
    for (int b = threadIdx.x; b < BATCH; b += 256) {
        const float* xr = src + (size_t)b*2016;
        float xv[FRAW];
        #pragma unroll
        for (int f=0; f<FRAW; ++f) xv[f] = xr[f];
        #pragma unroll
        for (int i=0; i<FCONV; ++i) {
            float y = fmaf(w0, xv[(i+18)%20], fmaf(w1, xv[(i+19)%20], fmaf(w2, xv[i%20], cb)));
            s += y; ss = fmaf(y, y, ss);
        }
    }
    __shared__ float rs[256], rq[256];
    rs[threadIdx.x]=s; rq[threadIdx.x]=ss;
    __syncthreads();
    for (int o=128; o>0; o>>=1){
        if (threadIdx.x < o){ rs[threadIdx.x]+=rs[threadIdx.x+o]; rq[threadIdx.x]+=rq[threadIdx.x+o]; }
        __syncthreads();
    }
    if (threadIdx.x == 0){
        const float N = (float)(BATCH*FCONV);
        float mu  = rs[0]/N;
        float var = rq[0]/N - mu*mu;
        float A   = rsqrtf(var + 1e-5f) * bn_w[0];
        stats[2*t]   = A;
        stats[2*t+1] = bn_b[0] - mu*A;
    }
}

// -------- kernel 2: conv + BN + ELU + maxpool (unchanged) -------------------
__global__ __launch_bounds__(256)
void feat_kernel(const float* __restrict__ x_enc, const float* __restrict__ y_enc,
                 const float* __restrict__ conv_w, const float* __restrict__ conv_b,
                 const float* __restrict__ stats, float* __restrict__ feat)
{
    const int t = blockIdx.x;
    const int b = blockIdx.y*256 + threadIdx.x;
    const float w0=conv_w[0], w1=conv_w[1], w2=conv_w[2], cb=conv_b[0];
    const float A = stats[2*t], Bc = stats[2*t+1];
    const float* xr = ((t<96) ? (x_enc + (size_t)t*21) : (y_enc + (size_t)(t-96)*21)) + (size_t)b*2016;
    float xv[FRAW];
    #pragma unroll
    for (int f=0; f<FRAW; ++f) xv[f] = xr[f];
    float yv[FCONV];
    #pragma unroll
    for (int i=0; i<FCONV; ++i) {
        float y = fmaf(w0, xv[(i+18)%20], fmaf(w1, xv[(i+19)%20], fmaf(w2, xv[i%20], cb)));
        y = fmaf(y, A, Bc);
        yv[i] = (y > 0.f) ? y : expm1f(y);
    }
    float* fo = feat + ((size_t)t*BATCH + b)*FCNN;
    #pragma unroll
    for (int i=0; i<FCNN; ++i) {
        float m = (i==0) ? fmaxf(yv[0], yv[1])
                         : fmaxf(yv[2*i-1], fmaxf(yv[2*i], yv[2*i+1]));
        fo[i] = m;
    }
}

// -------- kernel 3: unified-buffer pipelined MFMA LSTM ----------------------
// 256 blocks x 768 thr (12 waves), 1 block/CU, 16 rows/block.
//  waves 0-4 : L0(i)   = h0(i)   from V[c]  {feat(i), h0(i-1)}   (2 tiles)
//  waves 5-9 : L1(i-1) = h1(i-1) from V[c]  {h0(i-1), h1(i-2)}   (2 tiles)
//  waves 10-11: heads out(i-2): h0(i-2) from V[cp], h1(i-2) from V[c]
// ONE buffer family V (mod-3), K=96, single fp16 plane:
//   k 0..10 feat | 11..50 h0 | 51..55 ZERO | 56..95 h1   (1536 halves/buf)
// h0/h1 "boundary" is at k=56: 8-aligned, so heads pick the source buffer
// PER 8-k LANE GROUP: chunk1 (k32-63) -> q<3 (k<=55, h0+zeros) from V[cp],
// q==3 (k56-63, h1) from V[c]. This fixes R9's stale-h1 bug (it read h1 from
// V[cp] = h1(i-3)).
// View: V_i holds {feat(i), h0(i-1), h1(i-2)}. Iter i: c=i%3, cp=(i-1)%3,
// cn=(i+1)%3. Readers: L0,L1 <- V[c]; heads <- V[cp] (h0) + V[c] (h1).
// Writers (all -> V[cn], disjoint k): L0 k11-50; L1 k56-95; feat k0-10.
// V[x]: written at iter x-1, read at x (L0/L1, heads-h1) and x+1 (heads-h0),
// rewritten at x+2. No overlap.
// Precision: x/h single fp16 (predicted err ~1e-3 << 2.78e-2 thr); W hi/lo
// in registers (2 MFMA per chunk: Wh*x + Wl*x); heads W hi-only (proven).
__global__ __launch_bounds__(NTH, 3)
void lstm_kernel(const float* __restrict__ feat,
                 const float* __restrict__ w_ih0, const float* __restrict__ w_hh0, const float* __restrict__ b0,
                 const float* __restrict__ w_ih1, const float* __restrict__ w_hh1, const float* __restrict__ b1,
                 const float* __restrict__ w_gamma, const float* __restrict__ b_gamma,
                 const float* __restrict__ w_eta,   const float* __restrict__ b_eta,
                 float* __restrict__ out)
{
    __shared__ __align__(16) _Float16 V[3*1536];

    const int tid  = threadIdx.x;
    const int l    = tid & 63;
    const int wv   = tid >> 6;
    const int q    = l >> 4;
    const int mr   = l & 15;
    const int row0 = blockIdx.x * ROWSPB;
    const bool isL0 = (wv < 5);
    const bool isL1 = (wv >= 5 && wv < 10);

    // ---- zero LDS (k51-55 pad must stay zero forever) ----
    { uint32_t* z=(uint32_t*)V; for(int i=tid;i<2304;i+=NTH) z[i]=0u; }

    // =================== per-role setup ===================
    half8 a0h[2][2], a0l[2][2];            // L0: [tile][chunk] hi/lo
    half8 a1h[2][3], a1l[2][3];            // L1: [tile][chunk] hi/lo
    half8 ahd[3];                          // heads (hi only)
    f32x4 bias0[2]={{0,0,0,0},{0,0,0,0}}, bias1[2]={{0,0,0,0},{0,0,0,0}};
    f32x4 biash={0,0,0,0};
    int woH0[2]={0,0}, woH1[2]={0,0};
    int fW0=0, fW1=0; bool fV0=false, fV1=false;
    const float* fG0 = feat; const float* fG1 = feat;

    if (isL0){
        // unified k-space: k<11 feat (w_ih0), 11..50 h0 (w_hh0), >=51 zero
        #pragma unroll
        for (int g=0; g<2; ++g){
            const int uA = 4*(2*wv+g) + (mr >> 2);
            const int RA = (mr & 3)*40 + uA;           // torch row: gate-major
            #pragma unroll
            for (int cc=0; cc<2; ++cc){
                #pragma unroll
                for (int ii=0; ii<8; ++ii){
                    int k = 32*cc + 8*q + ii;
                    float v = (k<11) ? w_ih0[RA*11+k] : ((k<51) ? w_hh0[RA*40+k-11] : 0.f);
                    _Float16 h = (_Float16)v;
                    a0h[g][cc][ii]=h; a0l[g][cc][ii]=(_Float16)(v-(float)h);
                }
            }
            const int u = 4*(2*wv+g) + q;
            bias0[g][0]=b0[u]; bias0[g][1]=b0[40+u]; bias0[g][2]=b0[80+u]; bias0[g][3]=b0[120+u];
            woH0[g] = offk(11+u, mr);
        }
    } else if (isL1){
        // unified k-space: 11..50 h0 (w_ih1), 56..95 h1 (w_hh1), else zero
        const int wl = wv - 5;
        #pragma unroll
        for (int g=0; g<2; ++g){
            const int uA = 4*(2*wl+g) + (mr >> 2);
            const int RA = (mr & 3)*40 + uA;
            #pragma unroll
            for (int cc=0; cc<3; ++cc){
                #pragma unroll
                for (int ii=0; ii<8; ++ii){
                    int k = 32*cc + 8*q + ii;
                    float v = 0.f;
                    if (k>=11 && k<51)      v = w_ih1[RA*40 + (k-11)];
                    else if (k>=56)         v = w_hh1[RA*40 + (k-56)];
                    _Float16 h = (_Float16)v;
                    a1h[g][cc][ii]=h; a1l[g][cc][ii]=(_Float16)(v-(float)h);
                }
            }
            const int u = 4*(2*wl+g) + q;
            bias1[g][0]=b1[u]; bias1[g][1]=b1[40+u]; bias1[g][2]=b1[80+u]; bias1[g][3]=b1[120+u];
            woH1[g] = offk(56+u, mr);
        }
    } else {
        const int hw = wv - 10;                        // 0 or 1
        const int jo = 16*hw + mr;
        #pragma unroll
        for (int cc=0; cc<3; ++cc){
            #pragma unroll
            for (int ii=0; ii<8; ++ii){
                int k = 32*cc + 8*q + ii;
                float v = 0.f;
                if (jo < NOUT){
                    if (k>=11 && k<51) v = (jo==0) ? w_gamma[2*(k-11)]   : w_eta[(jo-1)*80 + 2*(k-11)];
                    else if (k>=56)    v = (jo==0) ? w_gamma[2*(k-56)+1] : w_eta[(jo-1)*80 + 2*(k-56)+1];
                }
                ahd[cc][ii] = (_Float16)v;
            }
        }
        #pragma unroll
        for (int e=0; e<4; ++e){
            int j2 = 16*hw + 4*q + e;
            biash[e] = (j2 < NOUT) ? ((j2==0) ? b_gamma[0] : b_eta[j2-1]) : 0.f;
        }
        const int hl = tid - 640;                      // 0..127
        int i0 = hl, i1 = hl + 128;
        fV0 = (i0 < ROWSPB*FCNN); fV1 = (i1 < ROWSPB*FCNN);
        { int r = i0/FCNN, f = i0 - FCNN*r; r &= 15; fW0 = offk(f, r);
          fG0 = feat + (size_t)(row0 + r)*FCNN + f; }
        { int ix = fV1 ? i1 : 0;
          int r = ix/FCNN, f = ix - FCNN*(ix/FCNN); r &= 15; fW1 = offk(f, r);
          fG1 = feat + (size_t)(row0 + r)*FCNN + f; }
    }

    __syncthreads();    // zero-init visible before feat(0) staging
    float fA0=0.f, fA1=0.f, fB0=0.f, fB1=0.f;
    if (!isL0 && !isL1){
        if (fV0) V[fW0] = (_Float16)fG0[0];            // feat(0) -> V[0]
        if (fV1) V[fW1] = (_Float16)fG1[0];
        const size_t fs = (size_t)BATCH*FCNN;          // preload feat(1) -> B slot
        if (fV0) fB0 = fG0[fs];
        if (fV1) fB1 = fG1[fs];
    }
    __syncthreads();

    float c0[2]={0.f,0.f}, c1[2]={0.f,0.f};
    int c=0, cp=2, cn=1;
    const size_t featStep = (size_t)BATCH*FCNN;

    for (int i=0; i<TSTEPS+2; ++i){     // 194 iterations, ONE barrier each
        if (isL0){
            if (i < TSTEPS){
                const _Float16* xb = V + c*1536 + l*8;
                half8 x0 = *(const half8*)(xb);
                half8 x1 = *(const half8*)(xb + 512);
                #pragma unroll
                for (int g=0; g<2; ++g){
                    f32x4 cA = bias0[g];
                    cA = MFMA16(a0h[g][0], x0, cA);
                    cA = MFMA16(a0l[g][0], x0, cA);
                    f32x4 cB = {0.f,0.f,0.f,0.f};
                    cB = MFMA16(a0h[g][1], x1, cB);
                    cB = MFMA16(a0l[g][1], x1, cB);
                    f32x4 acc = cA + cB;
                    float ig=sigm_(acc[0]), fg=sigm_(acc[1]), gv=tanh_(acc[2]), og=sigm_(acc[3]);
                    c0[g] = fmaf(fg, c0[g], ig*gv);
                    float h0v = og * tanh_(c0[g]);
                    V[cn*1536 + woH0[g]] = (_Float16)h0v;
                }
            }
        } else if (isL1){
            if (i >= 1 && i <= TSTEPS){
                const _Float16* yb = V + c*1536 + l*8;
                half8 y0 = *(const half8*)(yb);
                half8 y1 = *(const half8*)(yb + 512);
                half8 y2 = *(const half8*)(yb + 1024);
                #pragma unroll
                for (int g=0; g<2; ++g){
                    f32x4 cA = bias1[g];
                    cA = MFMA16(a1h[g][0], y0, cA);
                    cA = MFMA16(a1l[g][0], y0, cA);
                    f32x4 cB = {0.f,0.f,0.f,0.f};
                    cB = MFMA16(a1h[g][1], y1, cB);
                    cB = MFMA16(a1l[g][1], y1, cB);
                    f32x4 cC = {0.f,0.f,0.f,0.f};
                    cC = MFMA16(a1h[g][2], y2, cC);
                    cC = MFMA16(a1l[g][2], y2, cC);
                    f32x4 acc = (cA + cB) + cC;
                    float ig=sigm_(acc[0]), fg=sigm_(acc[1]), gv=tanh_(acc[2]), og=sigm_(acc[3]);
                    c1[g] = fmaf(fg, c1[g], ig*gv);
                    float h1v = og * tanh_(c1[g]);
                    V[cn*1536 + woH1[g]] = (_Float16)h1v;
                }
            }
        } else {
            // ---- feat staging: write feat(i+1) into V[cn] ----
            if (i < TSTEPS-1){
                float v0, v1;
                if ((i&1)==0){ v0=fB0; v1=fB1; } else { v0=fA0; v1=fA1; }
                if (fV0) V[cn*1536 + fW0] = (_Float16)v0;
                if (fV1) V[cn*1536 + fW1] = (_Float16)v1;
            }
            // ---- prefetch feat(i+2) into the opposite slot ----
            if (i+2 < TSTEPS){
                size_t o = (size_t)(i+2)*featStep;
                if ((i&1)==0){ if(fV0) fA0=fG0[o]; if(fV1) fA1=fG1[o]; }
                else         { if(fV0) fB0=fG0[o]; if(fV1) fB1=fG1[o]; }
            }
            // ---- heads: out(i-2). h0(i-2) in V[cp] (k<=55); h1(i-2) in V[c]
            // (k>=56). chunk1 straddles at k56 = 8-aligned -> per-q select.
            if (i >= 2){
                const _Float16* zp = V + cp*1536 + l*8;            // h0 source
                const _Float16* zc = V + c*1536  + l*8;            // h1 source
                half8 z0 = *(const half8*)(zp);                    // k0-31 (h0)
                half8 z1 = *(const half8*)(((q<3) ? zp : zc) + 512); // k32-63
                half8 z2 = *(const half8*)(zc + 1024);             // k64-95 (h1)
                f32x4 H = biash;
                H = MFMA16(ahd[0], z0, H);
                H = MFMA16(ahd[1], z1, H);
                H = MFMA16(ahd[2], z2, H);
                float* op = out + ((size_t)(i-2)*BATCH + row0 + mr)*NOUT;
                const int jb = 16*(wv-10) + 4*q;
                #pragma unroll
                for (int e=0; e<4; ++e){
                    int j2 = jb + e;
                    if (j2 < NOUT) op[j2] = softplus_(H[e]);
                }
            }
        }

        WGBAR();        // the single per-iteration barrier
        cp = c; c = cn; cn = (cn==2) ? 0 : cn+1;
    }
}

// ---------------------------------------------------------------------------
extern "C" void kernel_launch(void* const* d_in, const int* in_sizes, int n_in,
                              void* d_out, int out_size, void* d_ws, size_t ws_size,
                              hipStream_t stream)
{
    (void)in_sizes; (void)n_in; (void)out_size; (void)ws_size;
    const float* x_enc   = (const float*)d_in[0];
    const float* y_enc   = (const float*)d_in[3];
    const float* conv_w  = (const float*)d_in[5];
    const float* conv_b  = (const float*)d_in[6];
    const float* bn_w    = (const float*)d_in[7];
    const float* bn_b    = (const float*)d_in[8];
    const float* w_ih0   = (const float*)d_in[9];
    const float* w_hh0   = (const float*)d_in[10];
    const float* b0      = (const float*)d_in[11];
    const float* w_ih1   = (const float*)d_in[12];
    const float* w_hh1   = (const float*)d_in[13];
    const float* b1      = (const float*)d_in[14];
    const float* w_gamma = (const float*)d_in[15];
    const float* b_gamma = (const float*)d_in[16];
    const float* w_eta   = (const float*)d_in[17];
    const float* b_eta   = (const float*)d_in[18];

    float* out   = (float*)d_out;
    float* stats = (float*)d_ws;
    float* feat  = (float*)((char*)d_ws + FEAT_OFF);

    stats_kernel<<<TSTEPS, 256, 0, stream>>>(x_enc, y_enc, conv_w, conv_b, bn_w, bn_b, stats);
    feat_kernel<<<dim3(TSTEPS, BATCH/256), 256, 0, stream>>>(x_enc, y_enc, conv_w, conv_b, stats, feat);
    lstm_kernel<<<NBLK, NTH, 0, stream>>>(feat,
        w_ih0, w_hh0, b0, w_ih1, w_hh1, b1, w_gamma, b_gamma, w_eta, b_eta, out);
}

// Round 11
// 285.839 us; speedup vs baseline: 7.0287x; 1.4861x over previous
//
#include <hip/hip_runtime.h>
#include <cstdint>
#include <cstddef>

// ---------------- problem constants ----------------
#define TSTEPS 192
#define BATCH  4096
#define FRAW   20
#define FCONV  22
#define FCNN   11
#define HID    40
#define NOUT   21
#define ROWSPB 16
#define NTH    768              // 12 waves: 5 L0 + 5 L1 + 2 head/feat
#define NBLK   (BATCH/ROWSPB)   // 256 blocks = 1 block/CU

#define FEAT_OFF 4096           // ws: [0,1536) stats ; feat at byte offset 4096

typedef _Float16 half8 __attribute__((ext_vector_type(8)));
typedef float    f32x4 __attribute__((ext_vector_type(4)));
#define MFMA16(a,b,c) __builtin_amdgcn_mfma_f32_16x16x32_f16(a,b,c,0,0,0)

// LDS-only workgroup barrier (no vmcnt drain: head waves keep global ops in flight)
#define WGBAR() do{ \
    __builtin_amdgcn_sched_barrier(0); \
    asm volatile("s_waitcnt lgkmcnt(0)" ::: "memory"); \
    __builtin_amdgcn_s_barrier(); \
    __builtin_amdgcn_sched_barrier(0); \
}while(0)

__device__ __forceinline__ float sigm_(float x){ return 1.f/(1.f+__expf(-x)); }
__device__ __forceinline__ float tanh_(float x){ float e=__expf(2.f*x); return 1.f-2.f/(e+1.f); }
// softplus = max(x,0) + ln(1+e^-|x|) = max(x,0) + ln2*log2(1+e^-|x|)  (~7 ops)
__device__ __forceinline__ float softplus_(float x){
    float t = __expf(-fabsf(x));
    return fmaxf(x,0.f) + 0.6931471805599453f*__log2f(1.f+t);
}

// fragment-layout offset (halves) of logical k, batch-row mr:
// [chunk=k>>5][q=(k>>3)&3][mr][i=k&7]; chunk stride 512, q stride 128
__device__ __forceinline__ int offk(int k, int mr){
    return ((k>>5)*4 + ((k>>3)&3))*128 + mr*8 + (k&7);
}

// -------- kernel 1: per-t BN affine params (unchanged) ----------------------
__global__ __launch_bounds__(256)
void stats_kernel(const float* __restrict__ x_enc, const float* __restrict__ y_enc,
                  const float* __restrict__ conv_w, const float* __restrict__ conv_b,
                  const float* __restrict__ bn_w, const float* __restrict__ bn_b,
                  float* __restrict__ stats)
{
    const int t = blockIdx.x;
    const float w0=conv_w[0], w1=conv_w[1], w2=conv_w[2], cb=conv_b[0];
    const float* src = (t < 96) ? (x_enc + (size_t)t*21) : (y_enc + (size_t)(t-96)*21);
    float s=0.f, ss=0.f;
    for (int b = threadIdx.x; b < BATCH; b += 256) {
        const float* xr = src + (size_t)b*2016;
        float xv[FRAW];
        #pragma unroll
        for (int f=0; f<FRAW; ++f) xv[f] = xr[f];
        #pragma unroll
        for (int i=0; i<FCONV; ++i) {
            float y = fmaf(w0, xv[(i+18)%20], fmaf(w1, xv[(i+19)%20], fmaf(w2, xv[i%20], cb)));
            s += y; ss = fmaf(y, y, ss);
        }
    }
    __shared__ float rs[256], rq[256];
    rs[threadIdx.x]=s; rq[threadIdx.x]=ss;
    __syncthreads();
    for (int o=128; o>0; o>>=1){
        if (threadIdx.x < o){ rs[threadIdx.x]+=rs[threadIdx.x+o]; rq[threadIdx.x]+=rq[threadIdx.x+o]; }
        __syncthreads();
    }
    if (threadIdx.x == 0){
        const float N = (float)(BATCH*FCONV);
        float mu  = rs[0]/N;
        float var = rq[0]/N - mu*mu;
        float A   = rsqrtf(var + 1e-5f) * bn_w[0];
        stats[2*t]   = A;
        stats[2*t+1] = bn_b[0] - mu*A;
    }
}

// -------- kernel 2: conv + BN + ELU + maxpool (unchanged) -------------------
__global__ __launch_bounds__(256)
void feat_kernel(const float* __restrict__ x_enc, const float* __restrict__ y_enc,
                 const float* __restrict__ conv_w, const float* __restrict__ conv_b,
                 const float* __restrict__ stats, float* __restrict__ feat)
{
    const int t = blockIdx.x;
    const int b = blockIdx.y*256 + threadIdx.x;
    const float w0=conv_w[0], w1=conv_w[1], w2=conv_w[2], cb=conv_b[0];
    const float A = stats[2*t], Bc = stats[2*t+1];
    const float* xr = ((t<96) ? (x_enc + (size_t)t*21) : (y_enc + (size_t)(t-96)*21)) + (size_t)b*2016;
    float xv[FRAW];
    #pragma unroll
    for (int f=0; f<FRAW; ++f) xv[f] = xr[f];
    float yv[FCONV];
    #pragma unroll
    for (int i=0; i<FCONV; ++i) {
        float y = fmaf(w0, xv[(i+18)%20], fmaf(w1, xv[(i+19)%20], fmaf(w2, xv[i%20], cb)));
        y = fmaf(y, A, Bc);
        yv[i] = (y > 0.f) ? y : expm1f(y);
    }
    float* fo = feat + ((size_t)t*BATCH + b)*FCNN;
    #pragma unroll
    for (int i=0; i<FCNN; ++i) {
        float m = (i==0) ? fmaxf(yv[0], yv[1])
                         : fmaxf(yv[2*i-1], fmaxf(yv[2*i], yv[2*i+1]));
        fo[i] = m;
    }
}

// -------- kernel 3: unified-buffer pipelined MFMA LSTM (R10 dataflow) -------
// Identical structure/races to R10 (audited there); differences are codegen:
// role-split outer loops, unroll-6 (lcm of mod-2 parity and mod-3 buffers) so
// every LDS offset is a compile-time immediate off one hoisted base pointer.
// V (mod-3), K=96, single fp16 plane:
//   k 0..10 feat | 11..50 h0 | 51..55 ZERO | 56..95 h1   (1536 halves/buf)
// Iter i: c=i%3, cp=(i-1)%3, cn=(i+1)%3. Main loop i = 2+6m+k, so
// c=(k+2)%3, cp=(k+1)%3, cn=k%3, parity=k%2 — all constants per unroll slot.
__global__ __launch_bounds__(NTH, 3)
void lstm_kernel(const float* __restrict__ feat,
                 const float* __restrict__ w_ih0, const float* __restrict__ w_hh0, const float* __restrict__ b0,
                 const float* __restrict__ w_ih1, const float* __restrict__ w_hh1, const float* __restrict__ b1,
                 const float* __restrict__ w_gamma, const float* __restrict__ b_gamma,
                 const float* __restrict__ w_eta,   const float* __restrict__ b_eta,
                 float* __restrict__ out)
{
    __shared__ __align__(16) _Float16 V[3*1536];

    const int tid  = threadIdx.x;
    const int l    = tid & 63;
    const int wv   = tid >> 6;
    const int q    = l >> 4;
    const int mr   = l & 15;
    const int row0 = blockIdx.x * ROWSPB;
    const bool isL0 = (wv < 5);
    const bool isL1 = (wv >= 5 && wv < 10);

    // ---- zero LDS (k51-55 / k91-95 pads must stay zero forever) ----
    { uint32_t* z=(uint32_t*)V; for(int i=tid;i<2304;i+=NTH) z[i]=0u; }

    // =================== per-role setup (same as R10) ===================
    half8 a0h[2][2], a0l[2][2];
    half8 a1h[2][3], a1l[2][3];
    half8 ahd[3];
    f32x4 bias0[2]={{0,0,0,0},{0,0,0,0}}, bias1[2]={{0,0,0,0},{0,0,0,0}};
    f32x4 biash={0,0,0,0};
    int woH0[2]={0,0}, woH1[2]={0,0};
    int fW0=0, fW1=0; bool fV0=false, fV1=false;
    const float* fG0 = feat; const float* fG1 = feat;

    if (isL0){
        #pragma unroll
        for (int g=0; g<2; ++g){
            const int uA = 4*(2*wv+g) + (mr >> 2);
            const int RA = (mr & 3)*40 + uA;           // torch row: gate-major
            #pragma unroll
            for (int cc=0; cc<2; ++cc){
                #pragma unroll
                for (int ii=0; ii<8; ++ii){
                    int k = 32*cc + 8*q + ii;
                    float v = (k<11) ? w_ih0[RA*11+k] : ((k<51) ? w_hh0[RA*40+k-11] : 0.f);
                    _Float16 h = (_Float16)v;
                    a0h[g][cc][ii]=h; a0l[g][cc][ii]=(_Float16)(v-(float)h);
                }
            }
            const int u = 4*(2*wv+g) + q;
            bias0[g][0]=b0[u]; bias0[g][1]=b0[40+u]; bias0[g][2]=b0[80+u]; bias0[g][3]=b0[120+u];
            woH0[g] = offk(11+u, mr);
        }
    } else if (isL1){
        const int wl = wv - 5;
        #pragma unroll
        for (int g=0; g<2; ++g){
            const int uA = 4*(2*wl+g) + (mr >> 2);
            const int RA = (mr & 3)*40 + uA;
            #pragma unroll
            for (int cc=0; cc<3; ++cc){
                #pragma unroll
                for (int ii=0; ii<8; ++ii){
                    int k = 32*cc + 8*q + ii;
                    float v = 0.f;
                    if (k>=11 && k<51)      v = w_ih1[RA*40 + (k-11)];
                    else if (k>=56)         v = w_hh1[RA*40 + (k-56)];
                    _Float16 h = (_Float16)v;
                    a1h[g][cc][ii]=h; a1l[g][cc][ii]=(_Float16)(v-(float)h);
                }
            }
            const int u = 4*(2*wl+g) + q;
            bias1[g][0]=b1[u]; bias1[g][1]=b1[40+u]; bias1[g][2]=b1[80+u]; bias1[g][3]=b1[120+u];
            woH1[g] = offk(56+u, mr);
        }
    } else {
        const int hw = wv - 10;
        const int jo = 16*hw + mr;
        #pragma unroll
        for (int cc=0; cc<3; ++cc){
            #pragma unroll
            for (int ii=0; ii<8; ++ii){
                int k = 32*cc + 8*q + ii;
                float v = 0.f;
                if (jo < NOUT){
                    if (k>=11 && k<51) v = (jo==0) ? w_gamma[2*(k-11)]   : w_eta[(jo-1)*80 + 2*(k-11)];
                    else if (k>=56)    v = (jo==0) ? w_gamma[2*(k-56)+1] : w_eta[(jo-1)*80 + 2*(k-56)+1];
                }
                ahd[cc][ii] = (_Float16)v;
            }
        }
        #pragma unroll
        for (int e=0; e<4; ++e){
            int j2 = 16*hw + 4*q + e;
            biash[e] = (j2 < NOUT) ? ((j2==0) ? b_gamma[0] : b_eta[j2-1]) : 0.f;
        }
        const int hl = tid - 640;                      // 0..127
        int i0 = hl, i1 = hl + 128;
        fV0 = (i0 < ROWSPB*FCNN); fV1 = (i1 < ROWSPB*FCNN);
        { int r = i0/FCNN, f = i0 - FCNN*r; r &= 15; fW0 = offk(f, r);
          fG0 = feat + (size_t)(row0 + r)*FCNN + f; }
        { int ix = fV1 ? i1 : 0;
          int r = ix/FCNN, f = ix - FCNN*(ix/FCNN); r &= 15; fW1 = offk(f, r);
          fG1 = feat + (size_t)(row0 + r)*FCNN + f; }
    }

    __syncthreads();    // zero-init visible before feat(0) staging
    float fA0=0.f, fA1=0.f, fB0=0.f, fB1=0.f;
    if (!isL0 && !isL1){
        if (fV0) V[fW0] = (_Float16)fG0[0];            // feat(0) -> V[0]
        if (fV1) V[fW1] = (_Float16)fG1[0];
        const size_t fs = (size_t)BATCH*FCNN;          // preload feat(1)
        if (fV0) fB0 = fG0[fs];
        if (fV1) fB1 = fG1[fs];
    }
    __syncthreads();

    float c0[2]={0.f,0.f}, c1[2]={0.f,0.f};
    const size_t featStep = (size_t)BATCH*FCNN;
    const _Float16* Vr = V + l*8;                      // hoisted read base

    if (isL0){
        _Float16* wp0 = V + woH0[0];
        _Float16* wp1 = V + woH0[1];
        #define L0B(C,CN) do{ \
            half8 x0 = *(const half8*)(Vr + (C)*1536); \
            half8 x1 = *(const half8*)(Vr + (C)*1536 + 512); \
            { f32x4 acc = bias0[0]; \
              acc = MFMA16(a0h[0][0], x0, acc); \
              acc = MFMA16(a0l[0][0], x0, acc); \
              acc = MFMA16(a0h[0][1], x1, acc); \
              acc = MFMA16(a0l[0][1], x1, acc); \
              float ig=sigm_(acc[0]), fg=sigm_(acc[1]), gv=tanh_(acc[2]), og=sigm_(acc[3]); \
              c0[0] = fmaf(fg, c0[0], ig*gv); \
              wp0[(CN)*1536] = (_Float16)(og * tanh_(c0[0])); } \
            { f32x4 acc = bias0[1]; \
              acc = MFMA16(a0h[1][0], x0, acc); \
              acc = MFMA16(a0l[1][0], x0, acc); \
              acc = MFMA16(a0h[1][1], x1, acc); \
              acc = MFMA16(a0l[1][1], x1, acc); \
              float ig=sigm_(acc[0]), fg=sigm_(acc[1]), gv=tanh_(acc[2]), og=sigm_(acc[3]); \
              c0[1] = fmaf(fg, c0[1], ig*gv); \
              wp1[(CN)*1536] = (_Float16)(og * tanh_(c0[1])); } \
        }while(0)
        L0B(0,1); WGBAR();      // i = 0
        L0B(1,2); WGBAR();      // i = 1
        for (int m=0; m<32; ++m){
            #pragma unroll
            for (int k=0; k<6; ++k){
                const int i = 2 + 6*m + k;
                if (i < TSTEPS) L0B((k+2)%3, k%3);
                WGBAR();
            }
        }
        #undef L0B
    } else if (isL1){
        _Float16* wp0 = V + woH1[0];
        _Float16* wp1 = V + woH1[1];
        #define L1B(C,CN) do{ \
            half8 y0 = *(const half8*)(Vr + (C)*1536); \
            half8 y1 = *(const half8*)(Vr + (C)*1536 + 512); \
            half8 y2 = *(const half8*)(Vr + (C)*1536 + 1024); \
            { f32x4 cA = bias1[0]; \
              cA = MFMA16(a1h[0][0], y0, cA); cA = MFMA16(a1l[0][0], y0, cA); \
              cA = MFMA16(a1h[0][1], y1, cA); cA = MFMA16(a1l[0][1], y1, cA); \
              f32x4 cB = {0.f,0.f,0.f,0.f}; \
              cB = MFMA16(a1h[0][2], y2, cB); cB = MFMA16(a1l[0][2], y2, cB); \
              f32x4 acc = cA + cB; \
              float ig=sigm_(acc[0]), fg=sigm_(acc[1]), gv=tanh_(acc[2]), og=sigm_(acc[3]); \
              c1[0] = fmaf(fg, c1[0], ig*gv); \
              wp0[(CN)*1536] = (_Float16)(og * tanh_(c1[0])); } \
            { f32x4 cA = bias1[1]; \
              cA = MFMA16(a1h[1][0], y0, cA); cA = MFMA16(a1l[1][0], y0, cA); \
              cA = MFMA16(a1h[1][1], y1, cA); cA = MFMA16(a1l[1][1], y1, cA); \
              f32x4 cB = {0.f,0.f,0.f,0.f}; \
              cB = MFMA16(a1h[1][2], y2, cB); cB = MFMA16(a1l[1][2], y2, cB); \
              f32x4 acc = cA + cB; \
              float ig=sigm_(acc[0]), fg=sigm_(acc[1]), gv=tanh_(acc[2]), og=sigm_(acc[3]); \
              c1[1] = fmaf(fg, c1[1], ig*gv); \
              wp1[(CN)*1536] = (_Float16)(og * tanh_(c1[1])); } \
        }while(0)
        WGBAR();                // i = 0 (L1 idle)
        L1B(1,2); WGBAR();      // i = 1
        for (int m=0; m<32; ++m){
            #pragma unroll
            for (int k=0; k<6; ++k){
                const int i = 2 + 6*m + k;
                if (i <= TSTEPS) L1B((k+2)%3, k%3);
                WGBAR();
            }
        }
        #undef L1B
    } else {
        _Float16* fp0 = V + fW0;
        _Float16* fp1 = V + fW1;
        const int hw  = wv - 10;
        const int jb  = 16*hw + 4*q;
        float* outB = out + (size_t)(row0 + mr)*NOUT + jb;
        // feat(i+1) write + feat(i+2) prefetch (parity regs; PAR = i&1)
        #define HFEAT(CN,PAR,I) do{ \
            if ((I) < TSTEPS-1){ \
                float v0 = (PAR) ? fA0 : fB0; \
                float v1 = (PAR) ? fA1 : fB1; \
                if (fV0) fp0[(CN)*1536] = (_Float16)v0; \
                if (fV1) fp1[(CN)*1536] = (_Float16)v1; \
            } \
            if ((I)+2 < TSTEPS){ \
                size_t o = (size_t)((I)+2)*featStep; \
                if (PAR){ if(fV0) fB0=fG0[o]; if(fV1) fB1=fG1[o]; } \
                else    { if(fV0) fA0=fG0[o]; if(fV1) fA1=fG1[o]; } \
            } \
        }while(0)
        // heads out(i-2): h0 from V[cp] (k<=55), h1 from V[c] (k>=56)
        #define HOUT(C,CP,I) do{ \
            half8 z0 = *(const half8*)(Vr + (CP)*1536); \
            half8 z1 = *(const half8*)(Vr + ((q<3)?(CP):(C))*1536 + 512); \
            half8 z2 = *(const half8*)(Vr + (C)*1536 + 1024); \
            f32x4 H = biash; \
            H = MFMA16(ahd[0], z0, H); \
            H = MFMA16(ahd[1], z1, H); \
            H = MFMA16(ahd[2], z2, H); \
            float* op = outB + (size_t)((I)-2)*(BATCH*NOUT); \
            if (hw==0 || q==0){ \
                op[0]=softplus_(H[0]); op[1]=softplus_(H[1]); \
                op[2]=softplus_(H[2]); op[3]=softplus_(H[3]); \
            } else if (q==1){ \
                op[0]=softplus_(H[0]); \
            } \
        }while(0)
        HFEAT(1,0,0); WGBAR();      // i = 0
        HFEAT(2,1,1); WGBAR();      // i = 1
        for (int m=0; m<32; ++m){
            #pragma unroll
            for (int k=0; k<6; ++k){
                const int i = 2 + 6*m + k;
                HFEAT(k%3, k%2, i);
                HOUT((k+2)%3, (k+1)%3, i);
                WGBAR();
            }
        }
        #undef HFEAT
        #undef HOUT
    }
}

// ---------------------------------------------------------------------------
extern "C" void kernel_launch(void* const* d_in, const int* in_sizes, int n_in,
                              void* d_out, int out_size, void* d_ws, size_t ws_size,
                              hipStream_t stream)
{
    (void)in_sizes; (void)n_in; (void)out_size; (void)ws_size;
    const float* x_enc   = (const float*)d_in[0];
    const float* y_enc   = (const float*)d_in[3];
    const float* conv_w  = (const float*)d_in[5];
    const float* conv_b  = (const float*)d_in[6];
    const float* bn_w    = (const float*)d_in[7];
    const float* bn_b    = (const float*)d_in[8];
    const float* w_ih0   = (const float*)d_in[9];
    const float* w_hh0   = (const float*)d_in[10];
    const float* b0      = (const float*)d_in[11];
    const float* w_ih1   = (const float*)d_in[12];
    const float* w_hh1   = (const float*)d_in[13];
    const float* b1      = (const float*)d_in[14];
    const float* w_gamma = (const float*)d_in[15];
    const float* b_gamma = (const float*)d_in[16];
    const float* w_eta   = (const float*)d_in[17];
    const float* b_eta   = (const float*)d_in[18];

    float* out   = (float*)d_out;
    float* stats = (float*)d_ws;
    float* feat  = (float*)((char*)d_ws + FEAT_OFF);

    stats_kernel<<<TSTEPS, 256, 0, stream>>>(x_enc, y_enc, conv_w, conv_b, bn_w, bn_b, stats);
    feat_kernel<<<dim3(TSTEPS, BATCH/256), 256, 0, stream>>>(x_enc, y_enc, conv_w, conv_b, stats, feat);
    lstm_kernel<<<NBLK, NTH, 0, stream>>>(feat,
        w_ih0, w_hh0, b0, w_ih1, w_hh1, b1, w_gamma, b_gamma, w_eta, b_eta, out);
}

// Round 12
// 187.600 us; speedup vs baseline: 10.7094x; 1.5237x over previous
//
#include <hip/hip_runtime.h>
#include <cstdint>
#include <cstddef>

// ---------------- problem constants ----------------
#define TSTEPS 192
#define BATCH  4096
#define FRAW   20
#define FCONV  22
#define FCNN   11
#define HID    40
#define NOUT   21
#define ROWSPB 16
#define NTH    768              // 12 waves: 5 L0 + 5 L1 + 2 head/feat
#define NBLK   (BATCH/ROWSPB)   // 256 blocks = 1 block/CU

#define FEAT_OFF 4096           // ws: [0,1536) stats ; feat (fp16) at byte 4096

typedef _Float16 half8 __attribute__((ext_vector_type(8)));
typedef float    f32x4 __attribute__((ext_vector_type(4)));
#define MFMA16(a,b,c) __builtin_amdgcn_mfma_f32_16x16x32_f16(a,b,c,0,0,0)

// LDS-only workgroup barrier (no vmcnt drain: head waves keep global ops in flight)
#define WGBAR() do{ \
    __builtin_amdgcn_sched_barrier(0); \
    asm volatile("s_waitcnt lgkmcnt(0)" ::: "memory"); \
    __builtin_amdgcn_s_barrier(); \
    __builtin_amdgcn_sched_barrier(0); \
}while(0)

// fast reciprocal (v_rcp_f32, ~1 ULP) — avoids precise-div expansion (~9 instr)
__device__ __forceinline__ float rcp_(float x){ return __builtin_amdgcn_rcpf(x); }
__device__ __forceinline__ float sigm_(float x){ return rcp_(1.f + __expf(-x)); }
__device__ __forceinline__ float tanh_(float x){ return fmaf(-2.f, rcp_(__expf(2.f*x) + 1.f), 1.f); }
// softplus = max(x,0) + ln2*log2(1+e^-|x|)  (no division)
__device__ __forceinline__ float softplus_(float x){
    float t = __expf(-fabsf(x));
    return fmaxf(x,0.f) + 0.6931471805599453f*__log2f(1.f+t);
}

// fragment-layout offset (halves) of logical k, batch-row mr:
// [chunk=k>>5][q=(k>>3)&3][mr][i=k&7]; chunk stride 512, q stride 128
__device__ __forceinline__ int offk(int k, int mr){
    return ((k>>5)*4 + ((k>>3)&3))*128 + mr*8 + (k&7);
}

// -------- kernel 1: per-t BN affine params (unchanged) ----------------------
__global__ __launch_bounds__(256)
void stats_kernel(const float* __restrict__ x_enc, const float* __restrict__ y_enc,
                  const float* __restrict__ conv_w, const float* __restrict__ conv_b,
                  const float* __restrict__ bn_w, const float* __restrict__ bn_b,
                  float* __restrict__ stats)
{
    const int t = blockIdx.x;
    const float w0=conv_w[0], w1=conv_w[1], w2=conv_w[2], cb=conv_b[0];
    const float* src = (t < 96) ? (x_enc + (size_t)t*21) : (y_enc + (size_t)(t-96)*21);
    float s=0.f, ss=0.f;
    for (int b = threadIdx.x; b < BATCH; b += 256) {
        const float* xr = src + (size_t)b*2016;
        float xv[FRAW];
        #pragma unroll
        for (int f=0; f<FRAW; ++f) xv[f] = xr[f];
        #pragma unroll
        for (int i=0; i<FCONV; ++i) {
            float y = fmaf(w0, xv[(i+18)%20], fmaf(w1, xv[(i+19)%20], fmaf(w2, xv[i%20], cb)));
            s += y; ss = fmaf(y, y, ss);
        }
    }
    __shared__ float rs[256], rq[256];
    rs[threadIdx.x]=s; rq[threadIdx.x]=ss;
    __syncthreads();
    for (int o=128; o>0; o>>=1){
        if (threadIdx.x < o){ rs[threadIdx.x]+=rs[threadIdx.x+o]; rq[threadIdx.x]+=rq[threadIdx.x+o]; }
        __syncthreads();
    }
    if (threadIdx.x == 0){
        const float N = (float)(BATCH*FCONV);
        float mu  = rs[0]/N;
        float var = rq[0]/N - mu*mu;
        float A   = rsqrtf(var + 1e-5f) * bn_w[0];
        stats[2*t]   = A;
        stats[2*t+1] = bn_b[0] - mu*A;
    }
}

// -------- kernel 2: conv + BN + ELU + maxpool -> fp16 feat ------------------
__global__ __launch_bounds__(256)
void feat_kernel(const float* __restrict__ x_enc, const float* __restrict__ y_enc,
                 const float* __restrict__ conv_w, const float* __restrict__ conv_b,
                 const float* __restrict__ stats, _Float16* __restrict__ feat)
{
    const int t = blockIdx.x;
    const int b = blockIdx.y*256 + threadIdx.x;
    const float w0=conv_w[0], w1=conv_w[1], w2=conv_w[2], cb=conv_b[0];
    const float A = stats[2*t], Bc = stats[2*t+1];
    const float* xr = ((t<96) ? (x_enc + (size_t)t*21) : (y_enc + (size_t)(t-96)*21)) + (size_t)b*2016;
    float xv[FRAW];
    #pragma unroll
    for (int f=0; f<FRAW; ++f) xv[f] = xr[f];
    float yv[FCONV];
    #pragma unroll
    for (int i=0; i<FCONV; ++i) {
        float y = fmaf(w0, xv[(i+18)%20], fmaf(w1, xv[(i+19)%20], fmaf(w2, xv[i%20], cb)));
        y = fmaf(y, A, Bc);
        yv[i] = (y > 0.f) ? y : (__expf(y) - 1.f);   // ELU, no libm expm1
    }
    _Float16* fo = feat + ((size_t)t*BATCH + b)*FCNN;
    #pragma unroll
    for (int i=0; i<FCNN; ++i) {
        float m = (i==0) ? fmaxf(yv[0], yv[1])
                         : fmaxf(yv[2*i-1], fmaxf(yv[2*i], yv[2*i+1]));
        fo[i] = (_Float16)m;
    }
}

// -------- kernel 3: unified-buffer pipelined MFMA LSTM (R11 structure) ------
// Identical dataflow/races to R10/R11 (audited). V (mod-3), K=96, fp16 plane:
//   k 0..10 feat | 11..50 h0 | 51..55 ZERO | 56..95 h1   (1536 halves/buf)
// Iter i: c=i%3, cp=(i-1)%3, cn=(i+1)%3; main loop i=2+6m+k so all buffer
// indices are compile-time constants per unroll slot.
__global__ __launch_bounds__(NTH, 3)
void lstm_kernel(const _Float16* __restrict__ feat,
                 const float* __restrict__ w_ih0, const float* __restrict__ w_hh0, const float* __restrict__ b0,
                 const float* __restrict__ w_ih1, const float* __restrict__ w_hh1, const float* __restrict__ b1,
                 const float* __restrict__ w_gamma, const float* __restrict__ b_gamma,
                 const float* __restrict__ w_eta,   const float* __restrict__ b_eta,
                 float* __restrict__ out)
{
    __shared__ __align__(16) _Float16 V[3*1536];

    const int tid  = threadIdx.x;
    const int l    = tid & 63;
    const int wv   = tid >> 6;
    const int q    = l >> 4;
    const int mr   = l & 15;
    const int row0 = blockIdx.x * ROWSPB;
    const bool isL0 = (wv < 5);
    const bool isL1 = (wv >= 5 && wv < 10);

    // ---- zero LDS (k51-55 / k91-95 pads must stay zero forever) ----
    { uint32_t* z=(uint32_t*)V; for(int i=tid;i<2304;i+=NTH) z[i]=0u; }

    // =================== per-role setup ===================
    half8 a0h[2][2], a0l[2][2];
    half8 a1h[2][3], a1l[2][3];
    half8 ahd[3];
    f32x4 bias0[2]={{0,0,0,0},{0,0,0,0}}, bias1[2]={{0,0,0,0},{0,0,0,0}};
    f32x4 biash={0,0,0,0};
    int woH0[2]={0,0}, woH1[2]={0,0};
    int fW0=0, fW1=0; bool fV0=false, fV1=false;
    const _Float16* fG0 = feat; const _Float16* fG1 = feat;

    if (isL0){
        #pragma unroll
        for (int g=0; g<2; ++g){
            const int uA = 4*(2*wv+g) + (mr >> 2);
            const int RA = (mr & 3)*40 + uA;           // torch row: gate-major
            #pragma unroll
            for (int cc=0; cc<2; ++cc){
                #pragma unroll
                for (int ii=0; ii<8; ++ii){
                    int k = 32*cc + 8*q + ii;
                    float v = (k<11) ? w_ih0[RA*11+k] : ((k<51) ? w_hh0[RA*40+k-11] : 0.f);
                    _Float16 h = (_Float16)v;
                    a0h[g][cc][ii]=h; a0l[g][cc][ii]=(_Float16)(v-(float)h);
                }
            }
            const int u = 4*(2*wv+g) + q;
            bias0[g][0]=b0[u]; bias0[g][1]=b0[40+u]; bias0[g][2]=b0[80+u]; bias0[g][3]=b0[120+u];
            woH0[g] = offk(11+u, mr);
        }
    } else if (isL1){
        const int wl = wv - 5;
        #pragma unroll
        for (int g=0; g<2; ++g){
            const int uA = 4*(2*wl+g) + (mr >> 2);
            const int RA = (mr & 3)*40 + uA;
            #pragma unroll
            for (int cc=0; cc<3; ++cc){
                #pragma unroll
                for (int ii=0; ii<8; ++ii){
                    int k = 32*cc + 8*q + ii;
                    float v = 0.f;
                    if (k>=11 && k<51)      v = w_ih1[RA*40 + (k-11)];
                    else if (k>=56)         v = w_hh1[RA*40 + (k-56)];
                    _Float16 h = (_Float16)v;
                    a1h[g][cc][ii]=h; a1l[g][cc][ii]=(_Float16)(v-(float)h);
                }
            }
            const int u = 4*(2*wl+g) + q;
            bias1[g][0]=b1[u]; bias1[g][1]=b1[40+u]; bias1[g][2]=b1[80+u]; bias1[g][3]=b1[120+u];
            woH1[g] = offk(56+u, mr);
        }
    } else {
        const int hw = wv - 10;
        const int jo = 16*hw + mr;
        #pragma unroll
        for (int cc=0; cc<3; ++cc){
            #pragma unroll
            for (int ii=0; ii<8; ++ii){
                int k = 32*cc + 8*q + ii;
                float v = 0.f;
                if (jo < NOUT){
                    if (k>=11 && k<51) v = (jo==0) ? w_gamma[2*(k-11)]   : w_eta[(jo-1)*80 + 2*(k-11)];
                    else if (k>=56)    v = (jo==0) ? w_gamma[2*(k-56)+1] : w_eta[(jo-1)*80 + 2*(k-56)+1];
                }
                ahd[cc][ii] = (_Float16)v;
            }
        }
        #pragma unroll
        for (int e=0; e<4; ++e){
            int j2 = 16*hw + 4*q + e;
            biash[e] = (j2 < NOUT) ? ((j2==0) ? b_gamma[0] : b_eta[j2-1]) : 0.f;
        }
        const int hl = tid - 640;                      // 0..127
        int i0 = hl, i1 = hl + 128;
        fV0 = (i0 < ROWSPB*FCNN); fV1 = (i1 < ROWSPB*FCNN);
        { int r = i0/FCNN, f = i0 - FCNN*r; r &= 15; fW0 = offk(f, r);
          fG0 = feat + (size_t)(row0 + r)*FCNN + f; }
        { int ix = fV1 ? i1 : 0;
          int r = ix/FCNN, f = ix - FCNN*(ix/FCNN); r &= 15; fW1 = offk(f, r);
          fG1 = feat + (size_t)(row0 + r)*FCNN + f; }
    }

    __syncthreads();    // zero-init visible before feat(0) staging
    _Float16 fA0=(_Float16)0.f, fA1=(_Float16)0.f, fB0=(_Float16)0.f, fB1=(_Float16)0.f;
    if (!isL0 && !isL1){
        if (fV0) V[fW0] = fG0[0];                      // feat(0) -> V[0]
        if (fV1) V[fW1] = fG1[0];
        const size_t fs = (size_t)BATCH*FCNN;          // preload feat(1)
        if (fV0) fB0 = fG0[fs];
        if (fV1) fB1 = fG1[fs];
    }
    __syncthreads();

    float c0[2]={0.f,0.f}, c1[2]={0.f,0.f};
    const size_t featStep = (size_t)BATCH*FCNN;
    const _Float16* Vr = V + l*8;                      // hoisted read base

    if (isL0){
        _Float16* wp0 = V + woH0[0];
        _Float16* wp1 = V + woH0[1];
        #define L0B(C,CN) do{ \
            half8 x0 = *(const half8*)(Vr + (C)*1536); \
            half8 x1 = *(const half8*)(Vr + (C)*1536 + 512); \
            { f32x4 acc = bias0[0]; \
              acc = MFMA16(a0h[0][0], x0, acc); \
              acc = MFMA16(a0l[0][0], x0, acc); \
              acc = MFMA16(a0h[0][1], x1, acc); \
              acc = MFMA16(a0l[0][1], x1, acc); \
              float ig=sigm_(acc[0]), fg=sigm_(acc[1]), gv=tanh_(acc[2]), og=sigm_(acc[3]); \
              c0[0] = fmaf(fg, c0[0], ig*gv); \
              wp0[(CN)*1536] = (_Float16)(og * tanh_(c0[0])); } \
            { f32x4 acc = bias0[1]; \
              acc = MFMA16(a0h[1][0], x0, acc); \
              acc = MFMA16(a0l[1][0], x0, acc); \
              acc = MFMA16(a0h[1][1], x1, acc); \
              acc = MFMA16(a0l[1][1], x1, acc); \
              float ig=sigm_(acc[0]), fg=sigm_(acc[1]), gv=tanh_(acc[2]), og=sigm_(acc[3]); \
              c0[1] = fmaf(fg, c0[1], ig*gv); \
              wp1[(CN)*1536] = (_Float16)(og * tanh_(c0[1])); } \
        }while(0)
        L0B(0,1); WGBAR();      // i = 0
        L0B(1,2); WGBAR();      // i = 1
        for (int m=0; m<32; ++m){
            #pragma unroll
            for (int k=0; k<6; ++k){
                const int i = 2 + 6*m + k;
                if (i < TSTEPS) L0B((k+2)%3, k%3);
                WGBAR();
            }
        }
        #undef L0B
    } else if (isL1){
        _Float16* wp0 = V + woH1[0];
        _Float16* wp1 = V + woH1[1];
        #define L1B(C,CN) do{ \
            half8 y0 = *(const half8*)(Vr + (C)*1536); \
            half8 y1 = *(const half8*)(Vr + (C)*1536 + 512); \
            half8 y2 = *(const half8*)(Vr + (C)*1536 + 1024); \
            { f32x4 cA = bias1[0]; \
              cA = MFMA16(a1h[0][0], y0, cA); cA = MFMA16(a1l[0][0], y0, cA); \
              cA = MFMA16(a1h[0][1], y1, cA); cA = MFMA16(a1l[0][1], y1, cA); \
              f32x4 cB = {0.f,0.f,0.f,0.f}; \
              cB = MFMA16(a1h[0][2], y2, cB); cB = MFMA16(a1l[0][2], y2, cB); \
              f32x4 acc = cA + cB; \
              float ig=sigm_(acc[0]), fg=sigm_(acc[1]), gv=tanh_(acc[2]), og=sigm_(acc[3]); \
              c1[0] = fmaf(fg, c1[0], ig*gv); \
              wp0[(CN)*1536] = (_Float16)(og * tanh_(c1[0])); } \
            { f32x4 cA = bias1[1]; \
              cA = MFMA16(a1h[1][0], y0, cA); cA = MFMA16(a1l[1][0], y0, cA); \
              cA = MFMA16(a1h[1][1], y1, cA); cA = MFMA16(a1l[1][1], y1, cA); \
              f32x4 cB = {0.f,0.f,0.f,0.f}; \
              cB = MFMA16(a1h[1][2], y2, cB); cB = MFMA16(a1l[1][2], y2, cB); \
              f32x4 acc = cA + cB; \
              float ig=sigm_(acc[0]), fg=sigm_(acc[1]), gv=tanh_(acc[2]), og=sigm_(acc[3]); \
              c1[1] = fmaf(fg, c1[1], ig*gv); \
              wp1[(CN)*1536] = (_Float16)(og * tanh_(c1[1])); } \
        }while(0)
        WGBAR();                // i = 0 (L1 idle)
        L1B(1,2); WGBAR();      // i = 1
        for (int m=0; m<32; ++m){
            #pragma unroll
            for (int k=0; k<6; ++k){
                const int i = 2 + 6*m + k;
                if (i <= TSTEPS) L1B((k+2)%3, k%3);
                WGBAR();
            }
        }
        #undef L1B
    } else {
        _Float16* fp0 = V + fW0;
        _Float16* fp1 = V + fW1;
        const int hw  = wv - 10;
        const int jb  = 16*hw + 4*q;
        float* outB = out + (size_t)(row0 + mr)*NOUT + jb;
        #define HFEAT(CN,PAR,I) do{ \
            if ((I) < TSTEPS-1){ \
                _Float16 v0 = (PAR) ? fA0 : fB0; \
                _Float16 v1 = (PAR) ? fA1 : fB1; \
                if (fV0) fp0[(CN)*1536] = v0; \
                if (fV1) fp1[(CN)*1536] = v1; \
            } \
            if ((I)+2 < TSTEPS){ \
                size_t o = (size_t)((I)+2)*featStep; \
                if (PAR){ if(fV0) fB0=fG0[o]; if(fV1) fB1=fG1[o]; } \
                else    { if(fV0) fA0=fG0[o]; if(fV1) fA1=fG1[o]; } \
            } \
        }while(0)
        #define HOUT(C,CP,I) do{ \
            half8 z0 = *(const half8*)(Vr + (CP)*1536); \
            half8 z1 = *(const half8*)(Vr + ((q<3)?(CP):(C))*1536 + 512); \
            half8 z2 = *(const half8*)(Vr + (C)*1536 + 1024); \
            f32x4 H = biash; \
            H = MFMA16(ahd[0], z0, H); \
            H = MFMA16(ahd[1], z1, H); \
            H = MFMA16(ahd[2], z2, H); \
            float* op = outB + (size_t)((I)-2)*(BATCH*NOUT); \
            if (hw==0 || q==0){ \
                op[0]=softplus_(H[0]); op[1]=softplus_(H[1]); \
                op[2]=softplus_(H[2]); op[3]=softplus_(H[3]); \
            } else if (q==1){ \
                op[0]=softplus_(H[0]); \
            } \
        }while(0)
        HFEAT(1,0,0); WGBAR();      // i = 0
        HFEAT(2,1,1); WGBAR();      // i = 1
        for (int m=0; m<32; ++m){
            #pragma unroll
            for (int k=0; k<6; ++k){
                const int i = 2 + 6*m + k;
                HFEAT(k%3, k%2, i);
                HOUT((k+2)%3, (k+1)%3, i);
                WGBAR();
            }
        }
        #undef HFEAT
        #undef HOUT
    }
}

// ---------------------------------------------------------------------------
extern "C" void kernel_launch(void* const* d_in, const int* in_sizes, int n_in,
                              void* d_out, int out_size, void* d_ws, size_t ws_size,
                              hipStream_t stream)
{
    (void)in_sizes; (void)n_in; (void)out_size; (void)ws_size;
    const float* x_enc   = (const float*)d_in[0];
    const float* y_enc   = (const float*)d_in[3];
    const float* conv_w  = (const float*)d_in[5];
    const float* conv_b  = (const float*)d_in[6];
    const float* bn_w    = (const float*)d_in[7];
    const float* bn_b    = (const float*)d_in[8];
    const float* w_ih0   = (const float*)d_in[9];
    const float* w_hh0   = (const float*)d_in[10];
    const float* b0      = (const float*)d_in[11];
    const float* w_ih1   = (const float*)d_in[12];
    const float* w_hh1   = (const float*)d_in[13];
    const float* b1      = (const float*)d_in[14];
    const float* w_gamma = (const float*)d_in[15];
    const float* b_gamma = (const float*)d_in[16];
    const float* w_eta   = (const float*)d_in[17];
    const float* b_eta   = (const float*)d_in[18];

    float*     out   = (float*)d_out;
    float*     stats = (float*)d_ws;
    _Float16*  feat  = (_Float16*)((char*)d_ws + FEAT_OFF);

    stats_kernel<<<TSTEPS, 256, 0, stream>>>(x_enc, y_enc, conv_w, conv_b, bn_w, bn_b, stats);
    feat_kernel<<<dim3(TSTEPS, BATCH/256), 256, 0, stream>>>(x_enc, y_enc, conv_w, conv_b, stats, feat);
    lstm_kernel<<<NBLK, NTH, 0, stream>>>(feat,
        w_ih0, w_hh0, b0, w_ih1, w_hh1, b1, w_gamma, b_gamma, w_eta, b_eta, out);
}

// Round 14
// 170.718 us; speedup vs baseline: 11.7684x; 1.0989x over previous
//
#include <hip/hip_runtime.h>
#include <cstdint>
#include <cstddef>

// ---------------- problem constants ----------------
#define TSTEPS 192
#define BATCH  4096
#define FRAW   20
#define FCONV  22
#define FCNN   11
#define HID    40
#define NOUT   21
#define ROWSPB 16
#define NTH    768              // 12 waves: 5 L0 + 5 L1 + 2 head/feat
#define NBLK   (BATCH/ROWSPB)   // 256 blocks = 1 block/CU

#define FEAT_OFF 4096           // ws: feat (fp16) at byte 4096

typedef _Float16 half8 __attribute__((ext_vector_type(8)));
typedef float    f32x4 __attribute__((ext_vector_type(4)));
#define MFMA16(a,b,c) __builtin_amdgcn_mfma_f32_16x16x32_f16(a,b,c,0,0,0)

// LDS-only workgroup barrier (no vmcnt drain: head waves keep global ops in flight)
#define WGBAR() do{ \
    __builtin_amdgcn_sched_barrier(0); \
    asm volatile("s_waitcnt lgkmcnt(0)" ::: "memory"); \
    __builtin_amdgcn_s_barrier(); \
    __builtin_amdgcn_sched_barrier(0); \
}while(0)

// fast reciprocal (v_rcp_f32, ~1 ULP) — avoids precise-div expansion
__device__ __forceinline__ float rcp_(float x){ return __builtin_amdgcn_rcpf(x); }
__device__ __forceinline__ float sigm_(float x){ return rcp_(1.f + __expf(-x)); }
__device__ __forceinline__ float tanh_(float x){ return fmaf(-2.f, rcp_(__expf(2.f*x) + 1.f), 1.f); }
__device__ __forceinline__ float softplus_(float x){
    float t = __expf(-fabsf(x));
    return fmaxf(x,0.f) + 0.6931471805599453f*__log2f(1.f+t);
}

// fragment-layout offset (halves) of logical k, batch-row mr:
// [chunk=k>>5][q=(k>>3)&3][mr][i=k&7]; chunk stride 512, q stride 128
__device__ __forceinline__ int offk(int k, int mr){
    return ((k>>5)*4 + ((k>>3)&3))*128 + mr*8 + (k&7);
}

// -------- kernel 1: FUSED stats + conv/BN/ELU/pool -> fp16 feat -------------
// 192 blocks (one per t) x 1024 threads, 4 rows/thread held in registers
// across the block reduction -> x_enc/y_enc read ONCE (was twice + 2 launches)
__global__ __launch_bounds__(1024)
void statfeat_kernel(const float* __restrict__ x_enc, const float* __restrict__ y_enc,
                     const float* __restrict__ conv_w, const float* __restrict__ conv_b,
                     const float* __restrict__ bn_w, const float* __restrict__ bn_b,
                     _Float16* __restrict__ feat)
{
    const int t = blockIdx.x;
    const float w0=conv_w[0], w1=conv_w[1], w2=conv_w[2], cb=conv_b[0];
    const float* src = (t < 96) ? (x_enc + (size_t)t*21) : (y_enc + (size_t)(t-96)*21);

    float xv[4][FRAW];
    float s=0.f, ss=0.f;
    #pragma unroll
    for (int rr=0; rr<4; ++rr){
        const int row = threadIdx.x + 1024*rr;
        const float* xr = src + (size_t)row*2016;    // 96*21
        #pragma unroll
        for (int f=0; f<FRAW; ++f) xv[rr][f] = xr[f];
        #pragma unroll
        for (int i=0; i<FCONV; ++i){
            float y = fmaf(w0, xv[rr][(i+18)%20], fmaf(w1, xv[rr][(i+19)%20], fmaf(w2, xv[rr][i%20], cb)));
            s += y; ss = fmaf(y, y, ss);
        }
    }
    // wave reduce (64-wide) then 16-partial tree
    #pragma unroll
    for (int o=32; o>0; o>>=1){ s += __shfl_down(s,o); ss += __shfl_down(ss,o); }
    __shared__ float rs[16], rq[16], ab[2];
    const int wid = threadIdx.x >> 6, lid = threadIdx.x & 63;
    if (lid == 0){ rs[wid]=s; rq[wid]=ss; }
    __syncthreads();
    if (threadIdx.x == 0){
        float S=0.f, Q=0.f;
        #pragma unroll
        for (int i=0;i<16;++i){ S+=rs[i]; Q+=rq[i]; }
        const float N = (float)BATCH*(float)FCONV;
        float mu  = S/N;
        float var = Q/N - mu*mu;
        float A   = rsqrtf(var + 1e-5f) * bn_w[0];
        ab[0]=A; ab[1]=bn_b[0] - mu*A;
    }
    __syncthreads();
    const float A = ab[0], Bc = ab[1];

    #pragma unroll
    for (int rr=0; rr<4; ++rr){
        const int row = threadIdx.x + 1024*rr;
        float yv[FCONV];
        #pragma unroll
        for (int i=0; i<FCONV; ++i){
            float y = fmaf(w0, xv[rr][(i+18)%20], fmaf(w1, xv[rr][(i+19)%20], fmaf(w2, xv[rr][i%20], cb)));
            y = fmaf(y, A, Bc);
            yv[i] = (y > 0.f) ? y : (__expf(y) - 1.f);   // ELU
        }
        _Float16* fo = feat + ((size_t)t*BATCH + row)*FCNN;
        #pragma unroll
        for (int i=0; i<FCNN; ++i){
            float m = (i==0) ? fmaxf(yv[0], yv[1])
                             : fmaxf(yv[2*i-1], fmaxf(yv[2*i], yv[2*i+1]));
            fo[i] = (_Float16)m;
        }
    }
}

// -------- kernel 2: unified-buffer pipelined MFMA LSTM (R12 numerics) -------
// W hi/lo split in registers (REQUIRED: R13's fp16-single W failed at 0.031).
// x/h single fp16 in LDS (proven R10). Heads hi-only (proven R5).
// V (mod-3), K=96, fp16: k 0..10 feat | 11..50 h0 | 51..55 ZERO | 56..95 h1.
// Iter i: c=i%3, cp=(i-1)%3, cn=(i+1)%3; main loop i=2+6m+k so all buffer
// indices are compile-time constants per unroll slot. Races audited R10.
__global__ __launch_bounds__(NTH, 3)
void lstm_kernel(const _Float16* __restrict__ feat,
                 const float* __restrict__ w_ih0, const float* __restrict__ w_hh0, const float* __restrict__ b0,
                 const float* __restrict__ w_ih1, const float* __restrict__ w_hh1, const float* __restrict__ b1,
                 const float* __restrict__ w_gamma, const float* __restrict__ b_gamma,
                 const float* __restrict__ w_eta,   const float* __restrict__ b_eta,
                 float* __restrict__ out)
{
    __shared__ __align__(16) _Float16 V[3*1536];

    const int tid  = threadIdx.x;
    const int l    = tid & 63;
    const int wv   = tid >> 6;
    const int q    = l >> 4;
    const int mr   = l & 15;
    const int row0 = blockIdx.x * ROWSPB;
    const bool isL0 = (wv < 5);
    const bool isL1 = (wv >= 5 && wv < 10);

    // ---- zero LDS (k51-55 / k91-95 pads must stay zero forever) ----
    { uint32_t* z=(uint32_t*)V; for(int i=tid;i<2304;i+=NTH) z[i]=0u; }

    // =================== per-role setup ===================
    half8 a0h[2][2], a0l[2][2];
    half8 a1h[2][3], a1l[2][3];
    half8 ahd[3];
    f32x4 bias0[2]={{0,0,0,0},{0,0,0,0}}, bias1[2]={{0,0,0,0},{0,0,0,0}};
    f32x4 biash={0,0,0,0};
    int woH0[2]={0,0}, woH1[2]={0,0};
    int fW0=0, fW1=0; bool fV0=false, fV1=false;
    const _Float16* fG0 = feat; const _Float16* fG1 = feat;

    if (isL0){
        #pragma unroll
        for (int g=0; g<2; ++g){
            const int uA = 4*(2*wv+g) + (mr >> 2);
            const int RA = (mr & 3)*40 + uA;           // torch row: gate-major
            #pragma unroll
            for (int cc=0; cc<2; ++cc){
                #pragma unroll
                for (int ii=0; ii<8; ++ii){
                    int k = 32*cc + 8*q + ii;
                    float v = (k<11) ? w_ih0[RA*11+k] : ((k<51) ? w_hh0[RA*40+k-11] : 0.f);
                    _Float16 h = (_Float16)v;
                    a0h[g][cc][ii]=h; a0l[g][cc][ii]=(_Float16)(v-(float)h);
                }
            }
            const int u = 4*(2*wv+g) + q;
            bias0[g][0]=b0[u]; bias0[g][1]=b0[40+u]; bias0[g][2]=b0[80+u]; bias0[g][3]=b0[120+u];
            woH0[g] = offk(11+u, mr);
        }
    } else if (isL1){
        const int wl = wv - 5;
        #pragma unroll
        for (int g=0; g<2; ++g){
            const int uA = 4*(2*wl+g) + (mr >> 2);
            const int RA = (mr & 3)*40 + uA;
            #pragma unroll
            for (int cc=0; cc<3; ++cc){
                #pragma unroll
                for (int ii=0; ii<8; ++ii){
                    int k = 32*cc + 8*q + ii;
                    float v = 0.f;
                    if (k>=11 && k<51)      v = w_ih1[RA*40 + (k-11)];
                    else if (k>=56)         v = w_hh1[RA*40 + (k-56)];
                    _Float16 h = (_Float16)v;
                    a1h[g][cc][ii]=h; a1l[g][cc][ii]=(_Float16)(v-(float)h);
                }
            }
            const int u = 4*(2*wl+g) + q;
            bias1[g][0]=b1[u]; bias1[g][1]=b1[40+u]; bias1[g][2]=b1[80+u]; bias1[g][3]=b1[120+u];
            woH1[g] = offk(56+u, mr);
        }
    } else {
        const int hw = wv - 10;
        const int jo = 16*hw + mr;
        #pragma unroll
        for (int cc=0; cc<3; ++cc){
            #pragma unroll
            for (int ii=0; ii<8; ++ii){
                int k = 32*cc + 8*q + ii;
                float v = 0.f;
                if (jo < NOUT){
                    if (k>=11 && k<51) v = (jo==0) ? w_gamma[2*(k-11)]   : w_eta[(jo-1)*80 + 2*(k-11)];
                    else if (k>=56)    v = (jo==0) ? w_gamma[2*(k-56)+1] : w_eta[(jo-1)*80 + 2*(k-56)+1];
                }
                ahd[cc][ii] = (_Float16)v;
            }
        }
        #pragma unroll
        for (int e=0; e<4; ++e){
            int j2 = 16*hw + 4*q + e;
            biash[e] = (j2 < NOUT) ? ((j2==0) ? b_gamma[0] : b_eta[j2-1]) : 0.f;
        }
        const int hl = tid - 640;                      // 0..127
        int i0 = hl, i1 = hl + 128;
        fV0 = (i0 < ROWSPB*FCNN); fV1 = (i1 < ROWSPB*FCNN);
        { int r = i0/FCNN, f = i0 - FCNN*r; r &= 15; fW0 = offk(f, r);
          fG0 = feat + (size_t)(row0 + r)*FCNN + f; }
        { int ix = fV1 ? i1 : 0;
          int r = ix/FCNN, f = ix - FCNN*(ix/FCNN); r &= 15; fW1 = offk(f, r);
          fG1 = feat + (size_t)(row0 + r)*FCNN + f; }
    }

    __syncthreads();    // zero-init visible before feat(0) staging
    _Float16 fA0=(_Float16)0.f, fA1=(_Float16)0.f, fB0=(_Float16)0.f, fB1=(_Float16)0.f;
    if (!isL0 && !isL1){
        if (fV0) V[fW0] = fG0[0];                      // feat(0) -> V[0]
        if (fV1) V[fW1] = fG1[0];
        const size_t fs = (size_t)BATCH*FCNN;          // preload feat(1)
        if (fV0) fB0 = fG0[fs];
        if (fV1) fB1 = fG1[fs];
    }
    __syncthreads();

    float c0[2]={0.f,0.f}, c1[2]={0.f,0.f};
    const size_t featStep = (size_t)BATCH*FCNN;
    const _Float16* Vr = V + l*8;                      // hoisted read base

    if (isL0){
        _Float16* wp0 = V + woH0[0];
        _Float16* wp1 = V + woH0[1];
        #define L0B(C,CN) do{ \
            half8 x0 = *(const half8*)(Vr + (C)*1536); \
            half8 x1 = *(const half8*)(Vr + (C)*1536 + 512); \
            { f32x4 acc = bias0[0]; \
              acc = MFMA16(a0h[0][0], x0, acc); \
              acc = MFMA16(a0l[0][0], x0, acc); \
              acc = MFMA16(a0h[0][1], x1, acc); \
              acc = MFMA16(a0l[0][1], x1, acc); \
              float ig=sigm_(acc[0]), fg=sigm_(acc[1]), gv=tanh_(acc[2]), og=sigm_(acc[3]); \
              c0[0] = fmaf(fg, c0[0], ig*gv); \
              wp0[(CN)*1536] = (_Float16)(og * tanh_(c0[0])); } \
            { f32x4 acc = bias0[1]; \
              acc = MFMA16(a0h[1][0], x0, acc); \
              acc = MFMA16(a0l[1][0], x0, acc); \
              acc = MFMA16(a0h[1][1], x1, acc); \
              acc = MFMA16(a0l[1][1], x1, acc); \
              float ig=sigm_(acc[0]), fg=sigm_(acc[1]), gv=tanh_(acc[2]), og=sigm_(acc[3]); \
              c0[1] = fmaf(fg, c0[1], ig*gv); \
              wp1[(CN)*1536] = (_Float16)(og * tanh_(c0[1])); } \
        }while(0)
        L0B(0,1); WGBAR();      // i = 0
        L0B(1,2); WGBAR();      // i = 1
        for (int m=0; m<32; ++m){
            #pragma unroll
            for (int k=0; k<6; ++k){
                const int i = 2 + 6*m + k;
                if (i < TSTEPS) L0B((k+2)%3, k%3);
                WGBAR();
            }
        }
        #undef L0B
    } else if (isL1){
        _Float16* wp0 = V + woH1[0];
        _Float16* wp1 = V + woH1[1];
        #define L1B(C,CN) do{ \
            half8 y0 = *(const half8*)(Vr + (C)*1536); \
            half8 y1 = *(const half8*)(Vr + (C)*1536 + 512); \
            half8 y2 = *(const half8*)(Vr + (C)*1536 + 1024); \
            { f32x4 cA = bias1[0]; \
              cA = MFMA16(a1h[0][0], y0, cA); cA = MFMA16(a1l[0][0], y0, cA); \
              cA = MFMA16(a1h[0][1], y1, cA); cA = MFMA16(a1l[0][1], y1, cA); \
              f32x4 cB = {0.f,0.f,0.f,0.f}; \
              cB = MFMA16(a1h[0][2], y2, cB); cB = MFMA16(a1l[0][2], y2, cB); \
              f32x4 acc = cA + cB; \
              float ig=sigm_(acc[0]), fg=sigm_(acc[1]), gv=tanh_(acc[2]), og=sigm_(acc[3]); \
              c1[0] = fmaf(fg, c1[0], ig*gv); \
              wp0[(CN)*1536] = (_Float16)(og * tanh_(c1[0])); } \
            { f32x4 cA = bias1[1]; \
              cA = MFMA16(a1h[1][0], y0, cA); cA = MFMA16(a1l[1][0], y0, cA); \
              cA = MFMA16(a1h[1][1], y1, cA); cA = MFMA16(a1l[1][1], y1, cA); \
              f32x4 cB = {0.f,0.f,0.f,0.f}; \
              cB = MFMA16(a1h[1][2], y2, cB); cB = MFMA16(a1l[1][2], y2, cB); \
              f32x4 acc = cA + cB; \
              float ig=sigm_(acc[0]), fg=sigm_(acc[1]), gv=tanh_(acc[2]), og=sigm_(acc[3]); \
              c1[1] = fmaf(fg, c1[1], ig*gv); \
              wp1[(CN)*1536] = (_Float16)(og * tanh_(c1[1])); } \
        }while(0)
        WGBAR();                // i = 0 (L1 idle)
        L1B(1,2); WGBAR();      // i = 1
        for (int m=0; m<32; ++m){
            #pragma unroll
            for (int k=0; k<6; ++k){
                const int i = 2 + 6*m + k;
                if (i <= TSTEPS) L1B((k+2)%3, k%3);
                WGBAR();
            }
        }
        #undef L1B
    } else {
        _Float16* fp0 = V + fW0;
        _Float16* fp1 = V + fW1;
        const int hw  = wv - 10;
        const int jb  = 16*hw + 4*q;
        float* outB = out + (size_t)(row0 + mr)*NOUT + jb;
        #define HFEAT(CN,PAR,I) do{ \
            if ((I) < TSTEPS-1){ \
                _Float16 v0 = (PAR) ? fA0 : fB0; \
                _Float16 v1 = (PAR) ? fA1 : fB1; \
                if (fV0) fp0[(CN)*1536] = v0; \
                if (fV1) fp1[(CN)*1536] = v1; \
            } \
            if ((I)+2 < TSTEPS){ \
                size_t o = (size_t)((I)+2)*featStep; \
                if (PAR){ if(fV0) fB0=fG0[o]; if(fV1) fB1=fG1[o]; } \
                else    { if(fV0) fA0=fG0[o]; if(fV1) fA1=fG1[o]; } \
            } \
        }while(0)
        #define HOUT(C,CP,I) do{ \
            half8 z0 = *(const half8*)(Vr + (CP)*1536); \
            half8 z1 = *(const half8*)(Vr + ((q<3)?(CP):(C))*1536 + 512); \
            half8 z2 = *(const half8*)(Vr + (C)*1536 + 1024); \
            f32x4 H = biash; \
            H = MFMA16(ahd[0], z0, H); \
            H = MFMA16(ahd[1], z1, H); \
            H = MFMA16(ahd[2], z2, H); \
            float* op = outB + (size_t)((I)-2)*(BATCH*NOUT); \
            if (hw==0 || q==0){ \
                op[0]=softplus_(H[0]); op[1]=softplus_(H[1]); \
                op[2]=softplus_(H[2]); op[3]=softplus_(H[3]); \
            } else if (q==1){ \
                op[0]=softplus_(H[0]); \
            } \
        }while(0)
        HFEAT(1,0,0); WGBAR();      // i = 0
        HFEAT(2,1,1); WGBAR();      // i = 1
        for (int m=0; m<32; ++m){
            #pragma unroll
            for (int k=0; k<6; ++k){
                const int i = 2 + 6*m + k;
                HFEAT(k%3, k%2, i);
                HOUT((k+2)%3, (k+1)%3, i);
                WGBAR();
            }
        }
        #undef HFEAT
        #undef HOUT
    }
}

// ---------------------------------------------------------------------------
extern "C" void kernel_launch(void* const* d_in, const int* in_sizes, int n_in,
                              void* d_out, int out_size, void* d_ws, size_t ws_size,
                              hipStream_t stream)
{
    (void)in_sizes; (void)n_in; (void)out_size; (void)ws_size;
    const float* x_enc   = (const float*)d_in[0];
    const float* y_enc   = (const float*)d_in[3];
    const float* conv_w  = (const float*)d_in[5];
    const float* conv_b  = (const float*)d_in[6];
    const float* bn_w    = (const float*)d_in[7];
    const float* bn_b    = (const float*)d_in[8];
    const float* w_ih0   = (const float*)d_in[9];
    const float* w_hh0   = (const float*)d_in[10];
    const float* b0      = (const float*)d_in[11];
    const float* w_ih1   = (const float*)d_in[12];
    const float* w_hh1   = (const float*)d_in[13];
    const float* b1      = (const float*)d_in[14];
    const float* w_gamma = (const float*)d_in[15];
    const float* b_gamma = (const float*)d_in[16];
    const float* w_eta   = (const float*)d_in[17];
    const float* b_eta   = (const float*)d_in[18];

    float*     out   = (float*)d_out;
    _Float16*  feat  = (_Float16*)((char*)d_ws + FEAT_OFF);

    statfeat_kernel<<<TSTEPS, 1024, 0, stream>>>(x_enc, y_enc, conv_w, conv_b, bn_w, bn_b, feat);
    lstm_kernel<<<NBLK, NTH, 0, stream>>>(feat,
        w_ih0, w_hh0, b0, w_ih1, w_hh1, b1, w_gamma, b_gamma, w_eta, b_eta, out);
}